// Round 5
// baseline (829.697 us; speedup 1.0000x reference)
//
#include <hip/hip_runtime.h>
#include <hip/hip_bf16.h>
#include <math.h>

// ---- problem constants ----
#define NNODES   20000
#define NEDGES   320000
#define NGRAPHS  100
#define CC       64        // LATENT
#define FLATDIM  576       // C*(1+3+5)
#define POSIN    640       // FLAT + C
#define POSOUT   1600      // NRADII*IRRDIM
#define PAYL     200       // bf16: b0[64] b1[64] b2[64] sh[8]  -> 400B row (16B aligned)

__device__ __forceinline__ float silu_f(float x){ return x / (1.0f + __expf(-x)); }
__device__ __forceinline__ float sigm_f(float x){ return 1.0f / (1.0f + __expf(-x)); }
__device__ __forceinline__ unsigned pk_bf16(float lo, float hi){
    __hip_bfloat162 t;
    t.x = __float2bfloat16(lo);
    t.y = __float2bfloat16(hi);
    return *reinterpret_cast<unsigned*>(&t);
}
__device__ __forceinline__ float bf_lo(unsigned u){ return __uint_as_float(u << 16); }
__device__ __forceinline__ float bf_hi(unsigned u){ return __uint_as_float(u & 0xffff0000u); }

// ---- prep: w1t [64][8] (cols of w1), w2t [64][64] (cols of w2); flags; degree ----
__global__ void prep_kernel(const float* __restrict__ w1, const float* __restrict__ w2,
                            const int* __restrict__ n_node,
                            const int* __restrict__ receivers,
                            float* __restrict__ w1t, float* __restrict__ w2t,
                            int* __restrict__ flags, int* __restrict__ degree)
{
    int tid = blockIdx.x * blockDim.x + threadIdx.x;
    int stride = gridDim.x * blockDim.x;
    for (int i = tid; i < 8 * 64; i += stride) {
        int b = i / 64, k = i % 64;
        w1t[k * 8 + b] = w1[i];
    }
    for (int i = tid; i < 64 * 64; i += stride) {
        int k = i / 64, j = i % 64;
        w2t[k * 64 + j] = w2[j * 64 + k];
    }
    for (int e = tid; e < NEDGES; e += stride)
        atomicAdd(&degree[receivers[e]], 1);
    if (tid == 0) {
        int a = 0;
        for (int g = 0; g < NGRAPHS; g++) { flags[a] = g + 1; a += n_node[g]; }
    }
}

// ---- exclusive scan of degree[20000] -> start[20001], single block ----
__global__ __launch_bounds__(1024) void scan_kernel(const int* __restrict__ degree,
                                                    int* __restrict__ start)
{
    __shared__ int partial[1024];
    int t = threadIdx.x;
    int base = t * 20;
    int s = 0;
    int loc[20];
    for (int i = 0; i < 20; i++) {
        int idx = base + i;
        int d = (idx < NNODES) ? degree[idx] : 0;
        loc[i] = s;
        s += d;
    }
    partial[t] = s;
    __syncthreads();
    if (t == 0) {
        int run = 0;
        for (int i = 0; i < 1024; i++) { int x = partial[i]; partial[i] = run; run += x; }
        start[NNODES] = run;
    }
    __syncthreads();
    int off = partial[t];
    for (int i = 0; i < 20; i++) {
        int idx = base + i;
        if (idx < NNODES) start[idx] = off + loc[i];
    }
}

// 0..63 repeat macro (all register indices compile-time -> guaranteed SROA)
#define FOR64(M) M(0)M(1)M(2)M(3)M(4)M(5)M(6)M(7)M(8)M(9)M(10)M(11)M(12)M(13)M(14)M(15) \
                 M(16)M(17)M(18)M(19)M(20)M(21)M(22)M(23)M(24)M(25)M(26)M(27)M(28)M(29)M(30)M(31) \
                 M(32)M(33)M(34)M(35)M(36)M(37)M(38)M(39)M(40)M(41)M(42)M(43)M(44)M(45)M(46)M(47) \
                 M(48)M(49)M(50)M(51)M(52)M(53)M(54)M(55)M(56)M(57)M(58)M(59)M(60)M(61)M(62)M(63)
#define FOR24(M) M(0)M(1)M(2)M(3)M(4)M(5)M(6)M(7)M(8)M(9)M(10)M(11) \
                 M(12)M(13)M(14)M(15)M(16)M(17)M(18)M(19)M(20)M(21)M(22)M(23)

// stage-1: named outputs s1_j, wave-uniform scalar weight loads
#define S1C(j) float s1_##j; { const float* wc = w1t + (j) * 8; \
    s1_##j = silu_f(rb0*wc[0] + rb1*wc[1] + rb2*wc[2] + rb3*wc[3] + \
                    rb4*wc[4] + rb5*wc[5] + rb6*wc[6] + rb7*wc[7]); }
// stage-2 dot: 4 partial chains (ILP)
#define DT(j) dt[(j) & 3] += s1_##j * w2c[j];
// 24 float4 output accumulators
#define ADECL(i) float4 A##i;
#define AZERO(i) A##i = make_float4(0.f, 0.f, 0.f, 0.f);
#define AUP(i) { float4 wv4 = w3k4[i]; \
    A##i.x += hk * wv4.x; A##i.y += hk * wv4.y; A##i.z += hk * wv4.z; A##i.w += hk * wv4.w; }
// pack two accums (8 outputs) -> one uint4 store
#define SC(t) (hrow[(ob + (t)) & 63] * 0.25f)
#define ST2(ia, ib) { int ob = hbase + 4 * (ia); \
    uint4 wv; \
    wv.x = pk_bf16(A##ia.x * SC(0), A##ia.y * SC(1)); \
    wv.y = pk_bf16(A##ia.z * SC(2), A##ia.w * SC(3)); \
    wv.z = pk_bf16(A##ib.x * SC(4), A##ib.y * SC(5)); \
    wv.w = pk_bf16(A##ib.z * SC(6), A##ib.w * SC(7)); \
    prow4[hq + (ia) / 2] = wv; }

// ---- edge stage: stages 1-3 streamed; wide contiguous bf16 stores at CSR slot ----
__global__ __launch_bounds__(256, 2) void edge_kernel(
    const float* __restrict__ pos, const int* __restrict__ species,
    const int* __restrict__ senders, const int* __restrict__ receivers,
    const float* __restrict__ node_embed,
    const float* __restrict__ w1t, const float* __restrict__ w2t,
    const float* __restrict__ w3,
    const int* __restrict__ start, int* __restrict__ cursor,
    unsigned* __restrict__ payload)
{
    int e = blockIdx.x * blockDim.x + threadIdx.x;
    if (e >= NEDGES) return;
    int snd = senders[e];
    int rcv = receivers[e];
    int slot = start[rcv] + atomicAdd(&cursor[rcv], 1);

    float dx = pos[rcv * 3 + 0] - pos[snd * 3 + 0];
    float dy = pos[rcv * 3 + 1] - pos[snd * 3 + 1];
    float dz = pos[rcv * 3 + 2] - pos[snd * 3 + 2];
    float r = sqrtf(dx * dx + dy * dy + dz * dz);
    float rinv = 1.0f / (r + 1e-9f);
    float ux = dx * rinv, uy = dy * rinv, uz = dz * rinv;

    const float SQ3 = 1.7320508075688772f;
    const float S15 = 3.872983346207417f;
    const float S5  = 2.2360679774997896f;
    float sh0 = SQ3 * ux, sh1 = SQ3 * uy, sh2 = SQ3 * uz;
    float sh3 = S15 * ux * uy;
    float sh4 = S15 * uy * uz;
    float sh5 = 0.5f * S5 * (3.0f * uz * uz - 1.0f);
    float sh6 = S15 * ux * uz;
    float sh7 = 0.5f * S15 * (ux * ux - uy * uy);

    const float PI = 3.14159265358979323846f;
    float rc = r * 0.2f;
    float env = 0.5f * (__cosf(PI * fminf(rc, 1.0f)) + 1.0f);
    float scale = 0.6324555320336759f * rinv * env;
    float rb0 = scale * __sinf(1.0f * PI * rc);
    float rb1 = scale * __sinf(2.0f * PI * rc);
    float rb2 = scale * __sinf(3.0f * PI * rc);
    float rb3 = scale * __sinf(4.0f * PI * rc);
    float rb4 = scale * __sinf(5.0f * PI * rc);
    float rb5 = scale * __sinf(6.0f * PI * rc);
    float rb6 = scale * __sinf(7.0f * PI * rc);
    float rb7 = scale * __sinf(8.0f * PI * rc);

    // stage 1: s1_0..s1_63 named registers
    FOR64(S1C)

    int sp = species[snd];
    const float* hrow = node_embed + sp * 64;
    unsigned* prow = payload + (size_t)slot * (PAYL / 2);
    uint4* prow4 = reinterpret_cast<uint4*>(prow);

    FOR24(ADECL)
    // two half-passes over the 192 outputs (96 each -> 24 float4 accums)
    for (int h = 0; h < 2; h++) {
        int hbase = h * 96;
        int hq = h * 12;
        FOR24(AZERO)
        for (int k = 0; k < 64; k++) {
            const float* w2c = w2t + k * 64;      // wave-uniform -> scalar loads
            float dt[4] = {0.f, 0.f, 0.f, 0.f};
            FOR64(DT)
            float hk = silu_f((dt[0] + dt[1]) + (dt[2] + dt[3]));
            const float4* w3k4 = reinterpret_cast<const float4*>(w3 + k * 192 + hbase);
            FOR24(AUP)
        }
        ST2(0,1)  ST2(2,3)  ST2(4,5)  ST2(6,7)  ST2(8,9)  ST2(10,11)
        ST2(12,13) ST2(14,15) ST2(16,17) ST2(18,19) ST2(20,21) ST2(22,23)
    }
    prow4[24] = make_uint4(pk_bf16(sh0, sh1), pk_bf16(sh2, sh3),
                           pk_bf16(sh4, sh5), pk_bf16(sh6, sh7));
}

// ---- fused gather + node stage: one wave per node (4 waves/block) ----
__global__ __launch_bounds__(256, 4) void node_kernel(
    const unsigned* __restrict__ payload, const int* __restrict__ start,
    const int* __restrict__ species, const float* __restrict__ node_embed,
    const float* __restrict__ lin_w0, const float* __restrict__ lin_w1,
    const float* __restrict__ lin_w2, const float* __restrict__ skip_w,
    const float* __restrict__ gate_w, const float* __restrict__ focus_w,
    const float* __restrict__ focus_b, const int* __restrict__ flags,
    float* __restrict__ out_focus, float* __restrict__ focus_emb)
{
    int wave = threadIdx.x >> 6;
    int lane = threadIdx.x & 63;
    int n = blockIdx.x * 4 + wave;

    __shared__ float sa[4][9][64];
    __shared__ float hh[4][64];
    __shared__ float ss[4][64];

    // gather: dual accumulator sets to break the FMA dependency chain
    float a0 = 0, a1x = 0, a1y = 0, a1z = 0;
    float a2a = 0, a2b = 0, a2c = 0, a2d = 0, a2e = 0;
    float c0 = 0, c1x = 0, c1y = 0, c1z = 0;
    float c2a = 0, c2b = 0, c2c = 0, c2d = 0, c2e = 0;
    int s0 = start[n], s1 = start[n + 1];
    int i = s0;
    for (; i + 1 < s1; i += 2) {
        const unsigned short* pA = (const unsigned short*)(payload + (size_t)i * (PAYL / 2));
        const unsigned short* pB = (const unsigned short*)(payload + (size_t)(i + 1) * (PAYL / 2));
        float Ab0 = __uint_as_float(((unsigned)pA[lane]) << 16);
        float Ab1 = __uint_as_float(((unsigned)pA[64 + lane]) << 16);
        float Ab2 = __uint_as_float(((unsigned)pA[128 + lane]) << 16);
        uint4 Asv = *reinterpret_cast<const uint4*>(pA + 192);
        float Bb0 = __uint_as_float(((unsigned)pB[lane]) << 16);
        float Bb1 = __uint_as_float(((unsigned)pB[64 + lane]) << 16);
        float Bb2 = __uint_as_float(((unsigned)pB[128 + lane]) << 16);
        uint4 Bsv = *reinterpret_cast<const uint4*>(pB + 192);
        a0  += Ab0;
        a1x += Ab1 * bf_lo(Asv.x); a1y += Ab1 * bf_hi(Asv.x); a1z += Ab1 * bf_lo(Asv.y);
        a2a += Ab2 * bf_hi(Asv.y); a2b += Ab2 * bf_lo(Asv.z); a2c += Ab2 * bf_hi(Asv.z);
        a2d += Ab2 * bf_lo(Asv.w); a2e += Ab2 * bf_hi(Asv.w);
        c0  += Bb0;
        c1x += Bb1 * bf_lo(Bsv.x); c1y += Bb1 * bf_hi(Bsv.x); c1z += Bb1 * bf_lo(Bsv.y);
        c2a += Bb2 * bf_hi(Bsv.y); c2b += Bb2 * bf_lo(Bsv.z); c2c += Bb2 * bf_hi(Bsv.z);
        c2d += Bb2 * bf_lo(Bsv.w); c2e += Bb2 * bf_hi(Bsv.w);
    }
    if (i < s1) {
        const unsigned short* pA = (const unsigned short*)(payload + (size_t)i * (PAYL / 2));
        float Ab0 = __uint_as_float(((unsigned)pA[lane]) << 16);
        float Ab1 = __uint_as_float(((unsigned)pA[64 + lane]) << 16);
        float Ab2 = __uint_as_float(((unsigned)pA[128 + lane]) << 16);
        uint4 Asv = *reinterpret_cast<const uint4*>(pA + 192);
        a0  += Ab0;
        a1x += Ab1 * bf_lo(Asv.x); a1y += Ab1 * bf_hi(Asv.x); a1z += Ab1 * bf_lo(Asv.y);
        a2a += Ab2 * bf_hi(Asv.y); a2b += Ab2 * bf_lo(Asv.z); a2c += Ab2 * bf_hi(Asv.z);
        a2d += Ab2 * bf_lo(Asv.w); a2e += Ab2 * bf_hi(Asv.w);
    }
    a0 += c0; a1x += c1x; a1y += c1y; a1z += c1z;
    a2a += c2a; a2b += c2b; a2c += c2c; a2d += c2d; a2e += c2e;

    // ---- node stage (wave-local LDS) ----
    sa[wave][0][lane] = a0;
    sa[wave][1][lane] = a1x; sa[wave][2][lane] = a1y; sa[wave][3][lane] = a1z;
    sa[wave][4][lane] = a2a; sa[wave][5][lane] = a2b; sa[wave][6][lane] = a2c;
    sa[wave][7][lane] = a2d; sa[wave][8][lane] = a2e;
    int spn = species[n];
    hh[wave][lane] = node_embed[spn * 64 + lane];

    float s = 0.0f;
    const float* skipb = skip_w + spn * 4096;
    #pragma unroll 4
    for (int c = 0; c < 64; c++)
        s += sa[wave][0][c] * lin_w0[c * 64 + lane] + hh[wave][c] * skipb[c * 64 + lane];

    float v0 = 0, v1 = 0, v2 = 0, t0 = 0, t1 = 0, t2 = 0, t3 = 0, t4 = 0;
    #pragma unroll 4
    for (int c = 0; c < 64; c++) {
        float wa = lin_w1[c * 64 + lane];
        v0 += sa[wave][1][c] * wa; v1 += sa[wave][2][c] * wa; v2 += sa[wave][3][c] * wa;
        float wb = lin_w2[c * 64 + lane];
        t0 += sa[wave][4][c] * wb; t1 += sa[wave][5][c] * wb; t2 += sa[wave][6][c] * wb;
        t3 += sa[wave][7][c] * wb; t4 += sa[wave][8][c] * wb;
    }

    ss[wave][lane] = s;
    float g1a = 0.0f, g2a = 0.0f;
    #pragma unroll 4
    for (int c = 0; c < 64; c++) {
        float sc = ss[wave][c];
        g1a += sc * gate_w[c * 128 + lane];
        g2a += sc * gate_w[c * 128 + 64 + lane];
    }
    float g1 = sigm_f(g1a), g2 = sigm_f(g2a);
    float s_out = s * sigm_f(s);
    float vo0 = v0 * g1, vo1 = v1 * g1, vo2 = v2 * g1;
    float to0 = t0 * g2, to1 = t1 * g2, to2 = t2 * g2, to3 = t3 * g2, to4 = t4 * g2;

    float pfo = s_out * focus_w[lane]
              + vo0 * focus_w[64 + lane * 3 + 0]
              + vo1 * focus_w[64 + lane * 3 + 1]
              + vo2 * focus_w[64 + lane * 3 + 2]
              + to0 * focus_w[256 + lane * 5 + 0]
              + to1 * focus_w[256 + lane * 5 + 1]
              + to2 * focus_w[256 + lane * 5 + 2]
              + to3 * focus_w[256 + lane * 5 + 3]
              + to4 * focus_w[256 + lane * 5 + 4];
    #pragma unroll
    for (int off = 32; off > 0; off >>= 1) pfo += __shfl_down(pfo, off);
    if (lane == 0) out_focus[n] = pfo + focus_b[0];

    int fg = flags[n];
    if (fg) {
        float* fe = focus_emb + (size_t)(fg - 1) * FLATDIM;
        fe[lane] = s_out;
        fe[64 + lane * 3 + 0] = vo0;
        fe[64 + lane * 3 + 1] = vo1;
        fe[64 + lane * 3 + 2] = vo2;
        fe[256 + lane * 5 + 0] = to0;
        fe[256 + lane * 5 + 1] = to1;
        fe[256 + lane * 5 + 2] = to2;
        fe[256 + lane * 5 + 3] = to3;
        fe[256 + lane * 5 + 4] = to4;
    }
}

// ---- graph stage: block per graph ----
__global__ __launch_bounds__(256) void graph_kernel(
    const float* __restrict__ focus_emb, const int* __restrict__ target_species,
    const float* __restrict__ species_embed,
    const float* __restrict__ species_w, const float* __restrict__ species_b,
    const float* __restrict__ pos_w, const float* __restrict__ pos_b,
    float* __restrict__ out_species, float* __restrict__ out_pos)
{
    int g = blockIdx.x;
    int tid = threadIdx.x;
    __shared__ float pin[POSIN];
    const float* fe = focus_emb + (size_t)g * FLATDIM;
    for (int i = tid; i < FLATDIM; i += 256) pin[i] = fe[i];
    int tsp = target_species[g];
    if (tid < CC) pin[FLATDIM + tid] = species_embed[tsp * CC + tid];
    __syncthreads();

    if (tid < 5) {
        float a = species_b[tid];
        for (int k = 0; k < FLATDIM; k++) a += pin[k] * species_w[k * 5 + tid];
        out_species[g * 5 + tid] = a;
    }
    for (int o = tid; o < POSOUT; o += 256) {
        float a = pos_b[o];
        #pragma unroll 8
        for (int k = 0; k < POSIN; k++) a += pin[k] * pos_w[(size_t)k * POSOUT + o];
        out_pos[(size_t)g * POSOUT + o] = a;
    }
}

extern "C" void kernel_launch(void* const* d_in, const int* in_sizes, int n_in,
                              void* d_out, int out_size, void* d_ws, size_t ws_size,
                              hipStream_t stream) {
    const float* positions      = (const float*)d_in[0];
    const int*   species        = (const int*)  d_in[1];
    const int*   senders        = (const int*)  d_in[2];
    const int*   receivers      = (const int*)  d_in[3];
    const int*   n_node         = (const int*)  d_in[4];
    const int*   target_species = (const int*)  d_in[5];
    const float* species_embed  = (const float*)d_in[6];
    const float* node_embed     = (const float*)d_in[7];
    const float* radial_w1      = (const float*)d_in[8];
    const float* radial_w2      = (const float*)d_in[9];
    const float* radial_w3      = (const float*)d_in[10];
    const float* lin_w0         = (const float*)d_in[11];
    const float* lin_w1         = (const float*)d_in[12];
    const float* lin_w2         = (const float*)d_in[13];
    const float* skip_w         = (const float*)d_in[14];
    const float* gate_w         = (const float*)d_in[15];
    const float* focus_w        = (const float*)d_in[16];
    const float* focus_b        = (const float*)d_in[17];
    const float* species_w      = (const float*)d_in[18];
    const float* species_b      = (const float*)d_in[19];
    const float* pos_w          = (const float*)d_in[20];
    const float* pos_b          = (const float*)d_in[21];

    // ws layout: payload bf16 [320000*200] (= 320000*100 uints, 128MB)
    //          | degree[20000] cursor[20000] flags[20000] start[20001] (ints)
    //          | w1t[512] w2t[4096] focus_emb[57600] (floats)
    unsigned* payload = (unsigned*)d_ws;
    int* degree = (int*)(payload + (size_t)NEDGES * (PAYL / 2));
    int* cursor = degree + NNODES;
    int* flags  = cursor + NNODES;
    int* start  = flags + NNODES;
    float* w1t  = (float*)(start + NNODES + 1);
    float* w2t  = w1t + 512;
    float* focus_emb = w2t + 4096;

    hipMemsetAsync(degree, 0, 3 * NNODES * sizeof(int), stream);

    prep_kernel<<<128, 256, 0, stream>>>(radial_w1, radial_w2, n_node, receivers,
                                         w1t, w2t, flags, degree);
    scan_kernel<<<1, 1024, 0, stream>>>(degree, start);
    edge_kernel<<<(NEDGES + 255) / 256, 256, 0, stream>>>(
        positions, species, senders, receivers, node_embed, w1t, w2t, radial_w3,
        start, cursor, payload);

    float* out       = (float*)d_out;
    float* out_focus = out;
    float* out_spec  = out + NNODES;
    float* out_pos   = out + NNODES + NGRAPHS * 5;

    node_kernel<<<NNODES / 4, 256, 0, stream>>>(
        payload, start, species, node_embed,
        lin_w0, lin_w1, lin_w2, skip_w, gate_w, focus_w, focus_b, flags,
        out_focus, focus_emb);

    graph_kernel<<<NGRAPHS, 256, 0, stream>>>(
        focus_emb, target_species, species_embed, species_w, species_b,
        pos_w, pos_b, out_spec, out_pos);
}

// Round 6
// 444.057 us; speedup vs baseline: 1.8684x; 1.8684x over previous
//
#include <hip/hip_runtime.h>
#include <hip/hip_bf16.h>
#include <math.h>

// ---- problem constants ----
#define NNODES   20000
#define NEDGES   320000
#define NGRAPHS  100
#define CC       64        // LATENT
#define FLATDIM  576       // C*(1+3+5)
#define POSIN    640       // FLAT + C
#define POSOUT   1600      // NRADII*IRRDIM
#define PAYL     200       // bf16 row: b0[64] b1[64] b2[64] sh[8] -> 400B (25 uint4)

typedef __attribute__((ext_vector_type(8))) short bf16x8;
typedef __attribute__((ext_vector_type(4))) float f32x4;

__device__ __forceinline__ float silu_f(float x){ return x / (1.0f + __expf(-x)); }
__device__ __forceinline__ float sigm_f(float x){ return 1.0f / (1.0f + __expf(-x)); }
__device__ __forceinline__ unsigned pk_bf16(float lo, float hi){
    __hip_bfloat162 t;
    t.x = __float2bfloat16(lo);
    t.y = __float2bfloat16(hi);
    return *reinterpret_cast<unsigned*>(&t);
}
__device__ __forceinline__ unsigned short bf16u(float x){
    __hip_bfloat16 h = __float2bfloat16(x);
    return *reinterpret_cast<unsigned short*>(&h);
}
__device__ __forceinline__ float bf_lo(unsigned u){ return __uint_as_float(u << 16); }
__device__ __forceinline__ float bf_hi(unsigned u){ return __uint_as_float(u & 0xffff0000u); }

// ---- prep: pack w2 -> w2tn_g [n][k] bf16-pairs u32, w3 -> w3tn_g [o][k]; flags; degree ----
__global__ void prep_kernel(const float* __restrict__ w2, const float* __restrict__ w3,
                            const int* __restrict__ n_node,
                            const int* __restrict__ receivers,
                            unsigned* __restrict__ w2tn_g, unsigned* __restrict__ w3tn_g,
                            int* __restrict__ flags, int* __restrict__ degree)
{
    int tid = blockIdx.x * blockDim.x + threadIdx.x;
    int stride = gridDim.x * blockDim.x;
    for (int i = tid; i < 2048; i += stride) {          // w2: 64n x 32 k-pairs
        int n = i >> 5, k = (i & 31) * 2;
        w2tn_g[i] = pk_bf16(w2[k * 64 + n], w2[(k + 1) * 64 + n]);
    }
    for (int i = tid; i < 6144; i += stride) {          // w3: 192o x 32 k-pairs
        int o = i >> 5, k = (i & 31) * 2;
        w3tn_g[i] = pk_bf16(w3[k * 192 + o], w3[(k + 1) * 192 + o]);
    }
    for (int e = tid; e < NEDGES; e += stride)
        atomicAdd(&degree[receivers[e]], 1);
    if (tid == 0) {
        int a = 0;
        for (int g = 0; g < NGRAPHS; g++) { flags[a] = g + 1; a += n_node[g]; }
    }
}

// ---- exclusive scan of degree[20000] -> start[20001], single block ----
__global__ __launch_bounds__(1024) void scan_kernel(const int* __restrict__ degree,
                                                    int* __restrict__ start)
{
    __shared__ int partial[1024];
    int t = threadIdx.x;
    int base = t * 20;
    int s = 0;
    int loc[20];
    for (int i = 0; i < 20; i++) {
        int idx = base + i;
        int d = (idx < NNODES) ? degree[idx] : 0;
        loc[i] = s;
        s += d;
    }
    partial[t] = s;
    __syncthreads();
    if (t == 0) {
        int run = 0;
        for (int i = 0; i < 1024; i++) { int x = partial[i]; partial[i] = run; run += x; }
        start[NNODES] = run;
    }
    __syncthreads();
    int off = partial[t];
    for (int i = 0; i < 20; i++) {
        int idx = base + i;
        if (idx < NNODES) start[idx] = off + loc[i];
    }
}

// swizzled LDS byte offset for [row][128B] tiles: XOR row bits into 16B-slot bits (G4)
__device__ __forceinline__ int swz(int row, int kbyte){
    return row * 128 + (kbyte ^ ((row & 7) << 4));
}
__device__ __forceinline__ bf16x8 ld_frag(const unsigned char* base, int row, int kbyte){
    return *reinterpret_cast<const bf16x8*>(base + swz(row, kbyte));
}

// ---- edge stage: MFMA formulation. 64 edges per block, 4 waves. ----
__global__ __launch_bounds__(256, 2) void edge_kernel(
    const float* __restrict__ pos, const int* __restrict__ species,
    const int* __restrict__ senders, const int* __restrict__ receivers,
    const float* __restrict__ node_embed, const float* __restrict__ w1,
    const unsigned* __restrict__ w2tn_g, const unsigned* __restrict__ w3tn_g,
    const int* __restrict__ start, int* __restrict__ cursor,
    unsigned* __restrict__ payload)
{
    __shared__ __align__(16) unsigned char w2l[8192];    // [n=64][k=64] bf16 swizzled
    __shared__ __align__(16) unsigned char w3l[24576];   // [o=192][k=64] bf16 swizzled
    __shared__ __align__(16) unsigned char a2l[8192];    // hid1 then hid2 [m=64][k=64] bf16 swizzled
    __shared__ unsigned short hsl[64 * 64];              // sender embed bf16 [m][c]
    __shared__ __align__(16) unsigned short otl[64 * 200]; // out tile (payload rows)
    __shared__ float rbl[64 * 8];
    __shared__ int spl[64];
    __shared__ int slotl[64];

    int tid = threadIdx.x;

    // stage weights into LDS (swizzled)
    for (int i = tid; i < 2048; i += 256) {
        int n = i >> 5, kb = (i & 31) * 4;
        *reinterpret_cast<unsigned*>(w2l + swz(n, kb)) = w2tn_g[i];
    }
    for (int i = tid; i < 6144; i += 256) {
        int n = i >> 5, kb = (i & 31) * 4;
        *reinterpret_cast<unsigned*>(w3l + swz(n, kb)) = w3tn_g[i];
    }

    // ---- phase A: per-edge geometry + CSR slot (one thread per edge) ----
    if (tid < 64) {
        int e = blockIdx.x * 64 + tid;
        int snd = senders[e];
        int rcv = receivers[e];
        slotl[tid] = start[rcv] + atomicAdd(&cursor[rcv], 1);
        spl[tid] = species[snd];

        float dx = pos[rcv * 3 + 0] - pos[snd * 3 + 0];
        float dy = pos[rcv * 3 + 1] - pos[snd * 3 + 1];
        float dz = pos[rcv * 3 + 2] - pos[snd * 3 + 2];
        float r = sqrtf(dx * dx + dy * dy + dz * dz);
        float rinv = 1.0f / (r + 1e-9f);
        float ux = dx * rinv, uy = dy * rinv, uz = dz * rinv;

        const float SQ3 = 1.7320508075688772f;
        const float S15 = 3.872983346207417f;
        const float S5  = 2.2360679774997896f;
        otl[tid * 200 + 192] = bf16u(SQ3 * ux);
        otl[tid * 200 + 193] = bf16u(SQ3 * uy);
        otl[tid * 200 + 194] = bf16u(SQ3 * uz);
        otl[tid * 200 + 195] = bf16u(S15 * ux * uy);
        otl[tid * 200 + 196] = bf16u(S15 * uy * uz);
        otl[tid * 200 + 197] = bf16u(0.5f * S5 * (3.0f * uz * uz - 1.0f));
        otl[tid * 200 + 198] = bf16u(S15 * ux * uz);
        otl[tid * 200 + 199] = bf16u(0.5f * S15 * (ux * ux - uy * uy));

        const float PI = 3.14159265358979323846f;
        float rc = r * 0.2f;
        float env = 0.5f * (__cosf(PI * fminf(rc, 1.0f)) + 1.0f);
        float scale = 0.6324555320336759f * rinv * env;
        #pragma unroll
        for (int b = 0; b < 8; b++)
            rbl[tid * 8 + b] = scale * __sinf((float)(b + 1) * PI * rc);
    }
    __syncthreads();

    // ---- hs fill: hsl[m][c] = bf16(node_embed[sp_m][c]) ----
    {
        int m = tid >> 2, c0 = (tid & 3) * 16;
        const float* hr = node_embed + spl[m] * 64 + c0;
        #pragma unroll
        for (int i = 0; i < 16; i++) hsl[m * 64 + c0 + i] = bf16u(hr[i]);
    }

    // ---- stage 1 (VALU, K=8): hid1[m][j] = silu(rb . w1[:,j]) -> a2l bf16 ----
    {
        int m = tid & 63, jg = tid >> 6;
        float r0 = rbl[m * 8 + 0], r1 = rbl[m * 8 + 1], r2 = rbl[m * 8 + 2], r3 = rbl[m * 8 + 3];
        float r4 = rbl[m * 8 + 4], r5 = rbl[m * 8 + 5], r6 = rbl[m * 8 + 6], r7 = rbl[m * 8 + 7];
        #pragma unroll
        for (int jp = 0; jp < 8; jp++) {
            int j = jg * 16 + jp * 2;
            float h0 = silu_f(r0 * w1[j]       + r1 * w1[64 + j]  + r2 * w1[128 + j] + r3 * w1[192 + j]
                            + r4 * w1[256 + j] + r5 * w1[320 + j] + r6 * w1[384 + j] + r7 * w1[448 + j]);
            float h1 = silu_f(r0 * w1[j + 1]     + r1 * w1[64 + j + 1]  + r2 * w1[128 + j + 1] + r3 * w1[192 + j + 1]
                            + r4 * w1[256 + j + 1] + r5 * w1[320 + j + 1] + r6 * w1[384 + j + 1] + r7 * w1[448 + j + 1]);
            *reinterpret_cast<unsigned*>(a2l + swz(m, j * 2)) = pk_bf16(h0, h1);
        }
    }
    __syncthreads();

    // ---- stage 2 MFMA: hid2 = silu(hid1 @ w2), M=64 K=64 N=64 ----
    int w = tid >> 6, l = tid & 63;
    int lrow = l & 15;
    int lkb = (l >> 4) * 16;          // k-group byte offset within 64B k-half
    {
        bf16x8 aF0 = ld_frag(a2l, 16 * w + lrow, lkb);
        bf16x8 aF1 = ld_frag(a2l, 16 * w + lrow, 64 + lkb);
        f32x4 acc[4];
        #pragma unroll
        for (int nt = 0; nt < 4; nt++) {
            f32x4 c = {0.f, 0.f, 0.f, 0.f};
            bf16x8 b0 = ld_frag(w2l, nt * 16 + lrow, lkb);
            bf16x8 b1 = ld_frag(w2l, nt * 16 + lrow, 64 + lkb);
            c = __builtin_amdgcn_mfma_f32_16x16x32_bf16(aF0, b0, c, 0, 0, 0);
            c = __builtin_amdgcn_mfma_f32_16x16x32_bf16(aF1, b1, c, 0, 0, 0);
            acc[nt] = c;
        }
        __syncthreads();   // all reads of a2l complete before overwrite
        #pragma unroll
        for (int nt = 0; nt < 4; nt++) {
            int n = nt * 16 + (l & 15);
            #pragma unroll
            for (int r = 0; r < 4; r++) {
                int m = 16 * w + (l >> 4) * 4 + r;
                *reinterpret_cast<unsigned short*>(a2l + swz(m, n * 2)) = bf16u(silu_f(acc[nt][r]));
            }
        }
    }
    __syncthreads();

    // ---- stage 3 MFMA: wts = hid2 @ w3, M=64 K=64 N=192; epilogue *hs*0.25 ----
    {
        bf16x8 a30 = ld_frag(a2l, 16 * w + lrow, lkb);
        bf16x8 a31 = ld_frag(a2l, 16 * w + lrow, 64 + lkb);
        #pragma unroll
        for (int nt = 0; nt < 12; nt++) {
            f32x4 c = {0.f, 0.f, 0.f, 0.f};
            bf16x8 b0 = ld_frag(w3l, nt * 16 + lrow, lkb);
            bf16x8 b1 = ld_frag(w3l, nt * 16 + lrow, 64 + lkb);
            c = __builtin_amdgcn_mfma_f32_16x16x32_bf16(a30, b0, c, 0, 0, 0);
            c = __builtin_amdgcn_mfma_f32_16x16x32_bf16(a31, b1, c, 0, 0, 0);
            int o = nt * 16 + (l & 15);
            #pragma unroll
            for (int r = 0; r < 4; r++) {
                int m = 16 * w + (l >> 4) * 4 + r;
                float hsf = __uint_as_float(((unsigned)hsl[m * 64 + (o & 63)]) << 16);
                otl[m * 200 + o] = bf16u(c[r] * hsf * 0.25f);
            }
        }
    }
    __syncthreads();

    // ---- coalesced copy: out tile rows -> payload rows at CSR slots ----
    {
        const uint4* ot4 = reinterpret_cast<const uint4*>(otl);
        uint4* pay4 = reinterpret_cast<uint4*>(payload);
        for (int i = tid; i < 64 * 25; i += 256) {
            int row = i / 25, q = i - row * 25;
            pay4[(size_t)slotl[row] * 25 + q] = ot4[row * 25 + q];
        }
    }
}

// ---- fused gather + node stage: one wave per node (4 waves/block) ----
__global__ __launch_bounds__(256, 4) void node_kernel(
    const unsigned* __restrict__ payload, const int* __restrict__ start,
    const int* __restrict__ species, const float* __restrict__ node_embed,
    const float* __restrict__ lin_w0, const float* __restrict__ lin_w1,
    const float* __restrict__ lin_w2, const float* __restrict__ skip_w,
    const float* __restrict__ gate_w, const float* __restrict__ focus_w,
    const float* __restrict__ focus_b, const int* __restrict__ flags,
    float* __restrict__ out_focus, float* __restrict__ focus_emb)
{
    int wave = threadIdx.x >> 6;
    int lane = threadIdx.x & 63;
    int n = blockIdx.x * 4 + wave;

    __shared__ float sa[4][9][64];
    __shared__ float hh[4][64];
    __shared__ float ss[4][64];

    float a0 = 0, a1x = 0, a1y = 0, a1z = 0;
    float a2a = 0, a2b = 0, a2c = 0, a2d = 0, a2e = 0;
    float c0 = 0, c1x = 0, c1y = 0, c1z = 0;
    float c2a = 0, c2b = 0, c2c = 0, c2d = 0, c2e = 0;
    int s0 = start[n], s1 = start[n + 1];
    int i = s0;
    for (; i + 1 < s1; i += 2) {
        const unsigned short* pA = (const unsigned short*)(payload + (size_t)i * (PAYL / 2));
        const unsigned short* pB = (const unsigned short*)(payload + (size_t)(i + 1) * (PAYL / 2));
        float Ab0 = __uint_as_float(((unsigned)pA[lane]) << 16);
        float Ab1 = __uint_as_float(((unsigned)pA[64 + lane]) << 16);
        float Ab2 = __uint_as_float(((unsigned)pA[128 + lane]) << 16);
        uint4 Asv = *reinterpret_cast<const uint4*>(pA + 192);
        float Bb0 = __uint_as_float(((unsigned)pB[lane]) << 16);
        float Bb1 = __uint_as_float(((unsigned)pB[64 + lane]) << 16);
        float Bb2 = __uint_as_float(((unsigned)pB[128 + lane]) << 16);
        uint4 Bsv = *reinterpret_cast<const uint4*>(pB + 192);
        a0  += Ab0;
        a1x += Ab1 * bf_lo(Asv.x); a1y += Ab1 * bf_hi(Asv.x); a1z += Ab1 * bf_lo(Asv.y);
        a2a += Ab2 * bf_hi(Asv.y); a2b += Ab2 * bf_lo(Asv.z); a2c += Ab2 * bf_hi(Asv.z);
        a2d += Ab2 * bf_lo(Asv.w); a2e += Ab2 * bf_hi(Asv.w);
        c0  += Bb0;
        c1x += Bb1 * bf_lo(Bsv.x); c1y += Bb1 * bf_hi(Bsv.x); c1z += Bb1 * bf_lo(Bsv.y);
        c2a += Bb2 * bf_hi(Bsv.y); c2b += Bb2 * bf_lo(Bsv.z); c2c += Bb2 * bf_hi(Bsv.z);
        c2d += Bb2 * bf_lo(Bsv.w); c2e += Bb2 * bf_hi(Bsv.w);
    }
    if (i < s1) {
        const unsigned short* pA = (const unsigned short*)(payload + (size_t)i * (PAYL / 2));
        float Ab0 = __uint_as_float(((unsigned)pA[lane]) << 16);
        float Ab1 = __uint_as_float(((unsigned)pA[64 + lane]) << 16);
        float Ab2 = __uint_as_float(((unsigned)pA[128 + lane]) << 16);
        uint4 Asv = *reinterpret_cast<const uint4*>(pA + 192);
        a0  += Ab0;
        a1x += Ab1 * bf_lo(Asv.x); a1y += Ab1 * bf_hi(Asv.x); a1z += Ab1 * bf_lo(Asv.y);
        a2a += Ab2 * bf_hi(Asv.y); a2b += Ab2 * bf_lo(Asv.z); a2c += Ab2 * bf_hi(Asv.z);
        a2d += Ab2 * bf_lo(Asv.w); a2e += Ab2 * bf_hi(Asv.w);
    }
    a0 += c0; a1x += c1x; a1y += c1y; a1z += c1z;
    a2a += c2a; a2b += c2b; a2c += c2c; a2d += c2d; a2e += c2e;

    sa[wave][0][lane] = a0;
    sa[wave][1][lane] = a1x; sa[wave][2][lane] = a1y; sa[wave][3][lane] = a1z;
    sa[wave][4][lane] = a2a; sa[wave][5][lane] = a2b; sa[wave][6][lane] = a2c;
    sa[wave][7][lane] = a2d; sa[wave][8][lane] = a2e;
    int spn = species[n];
    hh[wave][lane] = node_embed[spn * 64 + lane];

    float s = 0.0f;
    const float* skipb = skip_w + spn * 4096;
    #pragma unroll 4
    for (int c = 0; c < 64; c++)
        s += sa[wave][0][c] * lin_w0[c * 64 + lane] + hh[wave][c] * skipb[c * 64 + lane];

    float v0 = 0, v1 = 0, v2 = 0, t0 = 0, t1 = 0, t2 = 0, t3 = 0, t4 = 0;
    #pragma unroll 4
    for (int c = 0; c < 64; c++) {
        float wa = lin_w1[c * 64 + lane];
        v0 += sa[wave][1][c] * wa; v1 += sa[wave][2][c] * wa; v2 += sa[wave][3][c] * wa;
        float wb = lin_w2[c * 64 + lane];
        t0 += sa[wave][4][c] * wb; t1 += sa[wave][5][c] * wb; t2 += sa[wave][6][c] * wb;
        t3 += sa[wave][7][c] * wb; t4 += sa[wave][8][c] * wb;
    }

    ss[wave][lane] = s;
    float g1a = 0.0f, g2a = 0.0f;
    #pragma unroll 4
    for (int c = 0; c < 64; c++) {
        float sc = ss[wave][c];
        g1a += sc * gate_w[c * 128 + lane];
        g2a += sc * gate_w[c * 128 + 64 + lane];
    }
    float g1 = sigm_f(g1a), g2 = sigm_f(g2a);
    float s_out = s * sigm_f(s);
    float vo0 = v0 * g1, vo1 = v1 * g1, vo2 = v2 * g1;
    float to0 = t0 * g2, to1 = t1 * g2, to2 = t2 * g2, to3 = t3 * g2, to4 = t4 * g2;

    float pfo = s_out * focus_w[lane]
              + vo0 * focus_w[64 + lane * 3 + 0]
              + vo1 * focus_w[64 + lane * 3 + 1]
              + vo2 * focus_w[64 + lane * 3 + 2]
              + to0 * focus_w[256 + lane * 5 + 0]
              + to1 * focus_w[256 + lane * 5 + 1]
              + to2 * focus_w[256 + lane * 5 + 2]
              + to3 * focus_w[256 + lane * 5 + 3]
              + to4 * focus_w[256 + lane * 5 + 4];
    #pragma unroll
    for (int off = 32; off > 0; off >>= 1) pfo += __shfl_down(pfo, off);
    if (lane == 0) out_focus[n] = pfo + focus_b[0];

    int fg = flags[n];
    if (fg) {
        float* fe = focus_emb + (size_t)(fg - 1) * FLATDIM;
        fe[lane] = s_out;
        fe[64 + lane * 3 + 0] = vo0;
        fe[64 + lane * 3 + 1] = vo1;
        fe[64 + lane * 3 + 2] = vo2;
        fe[256 + lane * 5 + 0] = to0;
        fe[256 + lane * 5 + 1] = to1;
        fe[256 + lane * 5 + 2] = to2;
        fe[256 + lane * 5 + 3] = to3;
        fe[256 + lane * 5 + 4] = to4;
    }
}

// ---- graph stage: block per graph ----
__global__ __launch_bounds__(256) void graph_kernel(
    const float* __restrict__ focus_emb, const int* __restrict__ target_species,
    const float* __restrict__ species_embed,
    const float* __restrict__ species_w, const float* __restrict__ species_b,
    const float* __restrict__ pos_w, const float* __restrict__ pos_b,
    float* __restrict__ out_species, float* __restrict__ out_pos)
{
    int g = blockIdx.x;
    int tid = threadIdx.x;
    __shared__ float pin[POSIN];
    const float* fe = focus_emb + (size_t)g * FLATDIM;
    for (int i = tid; i < FLATDIM; i += 256) pin[i] = fe[i];
    int tsp = target_species[g];
    if (tid < CC) pin[FLATDIM + tid] = species_embed[tsp * CC + tid];
    __syncthreads();

    if (tid < 5) {
        float a = species_b[tid];
        for (int k = 0; k < FLATDIM; k++) a += pin[k] * species_w[k * 5 + tid];
        out_species[g * 5 + tid] = a;
    }
    for (int o = tid; o < POSOUT; o += 256) {
        float a = pos_b[o];
        #pragma unroll 8
        for (int k = 0; k < POSIN; k++) a += pin[k] * pos_w[(size_t)k * POSOUT + o];
        out_pos[(size_t)g * POSOUT + o] = a;
    }
}

extern "C" void kernel_launch(void* const* d_in, const int* in_sizes, int n_in,
                              void* d_out, int out_size, void* d_ws, size_t ws_size,
                              hipStream_t stream) {
    const float* positions      = (const float*)d_in[0];
    const int*   species        = (const int*)  d_in[1];
    const int*   senders        = (const int*)  d_in[2];
    const int*   receivers      = (const int*)  d_in[3];
    const int*   n_node         = (const int*)  d_in[4];
    const int*   target_species = (const int*)  d_in[5];
    const float* species_embed  = (const float*)d_in[6];
    const float* node_embed     = (const float*)d_in[7];
    const float* radial_w1      = (const float*)d_in[8];
    const float* radial_w2      = (const float*)d_in[9];
    const float* radial_w3      = (const float*)d_in[10];
    const float* lin_w0         = (const float*)d_in[11];
    const float* lin_w1         = (const float*)d_in[12];
    const float* lin_w2         = (const float*)d_in[13];
    const float* skip_w         = (const float*)d_in[14];
    const float* gate_w         = (const float*)d_in[15];
    const float* focus_w        = (const float*)d_in[16];
    const float* focus_b        = (const float*)d_in[17];
    const float* species_w      = (const float*)d_in[18];
    const float* species_b      = (const float*)d_in[19];
    const float* pos_w          = (const float*)d_in[20];
    const float* pos_b          = (const float*)d_in[21];

    // ws layout: payload [320000*100 u32, 128MB]
    //          | degree[20000] cursor[20000] flags[20000] start[20001] (ints)
    //          | w2tn_g[2048 u32] w3tn_g[6144 u32] | focus_emb[57600 f32]
    unsigned* payload = (unsigned*)d_ws;
    int* degree = (int*)(payload + (size_t)NEDGES * (PAYL / 2));
    int* cursor = degree + NNODES;
    int* flags  = cursor + NNODES;
    int* start  = flags + NNODES;
    unsigned* w2tn_g = (unsigned*)(start + NNODES + 1);
    unsigned* w3tn_g = w2tn_g + 2048;
    float* focus_emb = (float*)(w3tn_g + 6144);

    hipMemsetAsync(degree, 0, 3 * NNODES * sizeof(int), stream);

    prep_kernel<<<128, 256, 0, stream>>>(radial_w2, radial_w3, n_node, receivers,
                                         w2tn_g, w3tn_g, flags, degree);
    scan_kernel<<<1, 1024, 0, stream>>>(degree, start);
    edge_kernel<<<NEDGES / 64, 256, 0, stream>>>(
        positions, species, senders, receivers, node_embed, radial_w1,
        w2tn_g, w3tn_g, start, cursor, payload);

    float* out       = (float*)d_out;
    float* out_focus = out;
    float* out_spec  = out + NNODES;
    float* out_pos   = out + NNODES + NGRAPHS * 5;

    node_kernel<<<NNODES / 4, 256, 0, stream>>>(
        payload, start, species, node_embed,
        lin_w0, lin_w1, lin_w2, skip_w, gate_w, focus_w, focus_b, flags,
        out_focus, focus_emb);

    graph_kernel<<<NGRAPHS, 256, 0, stream>>>(
        focus_emb, target_species, species_embed, species_w, species_b,
        pos_w, pos_b, out_spec, out_pos);
}

// Round 7
// 257.956 us; speedup vs baseline: 3.2164x; 1.7214x over previous
//
#include <hip/hip_runtime.h>
#include <hip/hip_bf16.h>
#include <math.h>

// ---- problem constants ----
#define NNODES   20000
#define NEDGES   320000
#define NGRAPHS  100
#define CC       64        // LATENT
#define FLATDIM  576       // C*(1+3+5)
#define POSIN    640       // FLAT + C
#define POSOUT   1600      // NRADII*IRRDIM
#define PAYL     200       // bf16 row: b0[64] b1[64] b2[64] sh[8] -> 400B (25 uint4)

typedef __attribute__((ext_vector_type(8))) short bf16x8;
typedef __attribute__((ext_vector_type(4))) float f32x4;

__device__ __forceinline__ float silu_f(float x){ return x / (1.0f + __expf(-x)); }
__device__ __forceinline__ float sigm_f(float x){ return 1.0f / (1.0f + __expf(-x)); }
__device__ __forceinline__ unsigned pk_bf16(float lo, float hi){
    __hip_bfloat162 t;
    t.x = __float2bfloat16(lo);
    t.y = __float2bfloat16(hi);
    return *reinterpret_cast<unsigned*>(&t);
}
__device__ __forceinline__ unsigned short bf16u(float x){
    __hip_bfloat16 h = __float2bfloat16(x);
    return *reinterpret_cast<unsigned short*>(&h);
}
__device__ __forceinline__ float bf_lo(unsigned u){ return __uint_as_float(u << 16); }
__device__ __forceinline__ float bf_hi(unsigned u){ return __uint_as_float(u & 0xffff0000u); }

// ---- prep: pack w2/w3 n-major bf16 pairs; pack pos_w bf16 pairs; flags; degree ----
__global__ void prep_kernel(const float* __restrict__ w2, const float* __restrict__ w3,
                            const float* __restrict__ pos_w,
                            const int* __restrict__ n_node,
                            const int* __restrict__ receivers,
                            unsigned* __restrict__ w2tn_g, unsigned* __restrict__ w3tn_g,
                            unsigned* __restrict__ posw_bf,
                            int* __restrict__ flags, int* __restrict__ degree)
{
    int tid = blockIdx.x * blockDim.x + threadIdx.x;
    int stride = gridDim.x * blockDim.x;
    for (int i = tid; i < 2048; i += stride) {          // w2: 64n x 32 k-pairs
        int n = i >> 5, k = (i & 31) * 2;
        w2tn_g[i] = pk_bf16(w2[k * 64 + n], w2[(k + 1) * 64 + n]);
    }
    for (int i = tid; i < 6144; i += stride) {          // w3: 192o x 32 k-pairs
        int o = i >> 5, k = (i & 31) * 2;
        w3tn_g[i] = pk_bf16(w3[k * 192 + o], w3[(k + 1) * 192 + o]);
    }
    for (int i = tid; i < 640 * 800; i += stride) {     // pos_w: [640][800 o-pairs]
        int k = i / 800, o = (i - k * 800) * 2;
        posw_bf[i] = pk_bf16(pos_w[(size_t)k * 1600 + o], pos_w[(size_t)k * 1600 + o + 1]);
    }
    for (int e = tid; e < NEDGES; e += stride)
        atomicAdd(&degree[receivers[e]], 1);
    if (tid == 0) {
        int a = 0;
        for (int g = 0; g < NGRAPHS; g++) { flags[a] = g + 1; a += n_node[g]; }
    }
}

// ---- exclusive scan of degree[20000] -> start[20001], single block ----
__global__ __launch_bounds__(1024) void scan_kernel(const int* __restrict__ degree,
                                                    int* __restrict__ start)
{
    __shared__ int partial[1024];
    int t = threadIdx.x;
    int base = t * 20;
    int s = 0;
    int loc[20];
    for (int i = 0; i < 20; i++) {
        int idx = base + i;
        int d = (idx < NNODES) ? degree[idx] : 0;
        loc[i] = s;
        s += d;
    }
    partial[t] = s;
    __syncthreads();
    if (t == 0) {
        int run = 0;
        for (int i = 0; i < 1024; i++) { int x = partial[i]; partial[i] = run; run += x; }
        start[NNODES] = run;
    }
    __syncthreads();
    int off = partial[t];
    for (int i = 0; i < 20; i++) {
        int idx = base + i;
        if (idx < NNODES) start[idx] = off + loc[i];
    }
}

// swizzled LDS byte offset for [row][128B] tiles: XOR row bits into 16B-slot bits (G4)
__device__ __forceinline__ int swz(int row, int kbyte){
    return row * 128 + (kbyte ^ ((row & 7) << 4));
}
__device__ __forceinline__ bf16x8 ld_frag(const unsigned char* base, int row, int kbyte){
    return *reinterpret_cast<const bf16x8*>(base + swz(row, kbyte));
}

// ---- edge stage: MFMA formulation. 64 edges per block, 4 waves. ----
__global__ __launch_bounds__(256, 2) void edge_kernel(
    const float* __restrict__ pos, const int* __restrict__ species,
    const int* __restrict__ senders, const int* __restrict__ receivers,
    const float* __restrict__ node_embed, const float* __restrict__ w1,
    const unsigned* __restrict__ w2tn_g, const unsigned* __restrict__ w3tn_g,
    const int* __restrict__ start, int* __restrict__ cursor,
    unsigned* __restrict__ payload)
{
    __shared__ __align__(16) unsigned char w2l[8192];    // [n=64][k=64] bf16 swizzled
    __shared__ __align__(16) unsigned char w3l[24576];   // [o=192][k=64] bf16 swizzled
    __shared__ __align__(16) unsigned char a2l[8192];    // hid1 then hid2 [m=64][k=64] bf16 swizzled
    __shared__ unsigned short hsl[64 * 64];              // sender embed bf16 [m][c]
    __shared__ __align__(16) unsigned short otl[64 * 200]; // out tile (payload rows)
    __shared__ float rbl[64 * 8];
    __shared__ int spl[64];
    __shared__ int slotl[64];

    int tid = threadIdx.x;

    // stage weights into LDS (swizzled)
    for (int i = tid; i < 2048; i += 256) {
        int n = i >> 5, kb = (i & 31) * 4;
        *reinterpret_cast<unsigned*>(w2l + swz(n, kb)) = w2tn_g[i];
    }
    for (int i = tid; i < 6144; i += 256) {
        int n = i >> 5, kb = (i & 31) * 4;
        *reinterpret_cast<unsigned*>(w3l + swz(n, kb)) = w3tn_g[i];
    }

    // ---- phase A: per-edge geometry + CSR slot (one thread per edge) ----
    if (tid < 64) {
        int e = blockIdx.x * 64 + tid;
        int snd = senders[e];
        int rcv = receivers[e];
        slotl[tid] = start[rcv] + atomicAdd(&cursor[rcv], 1);
        spl[tid] = species[snd];

        float dx = pos[rcv * 3 + 0] - pos[snd * 3 + 0];
        float dy = pos[rcv * 3 + 1] - pos[snd * 3 + 1];
        float dz = pos[rcv * 3 + 2] - pos[snd * 3 + 2];
        float r = sqrtf(dx * dx + dy * dy + dz * dz);
        float rinv = 1.0f / (r + 1e-9f);
        float ux = dx * rinv, uy = dy * rinv, uz = dz * rinv;

        const float SQ3 = 1.7320508075688772f;
        const float S15 = 3.872983346207417f;
        const float S5  = 2.2360679774997896f;
        otl[tid * 200 + 192] = bf16u(SQ3 * ux);
        otl[tid * 200 + 193] = bf16u(SQ3 * uy);
        otl[tid * 200 + 194] = bf16u(SQ3 * uz);
        otl[tid * 200 + 195] = bf16u(S15 * ux * uy);
        otl[tid * 200 + 196] = bf16u(S15 * uy * uz);
        otl[tid * 200 + 197] = bf16u(0.5f * S5 * (3.0f * uz * uz - 1.0f));
        otl[tid * 200 + 198] = bf16u(S15 * ux * uz);
        otl[tid * 200 + 199] = bf16u(0.5f * S15 * (ux * ux - uy * uy));

        const float PI = 3.14159265358979323846f;
        float rc = r * 0.2f;
        float env = 0.5f * (__cosf(PI * fminf(rc, 1.0f)) + 1.0f);
        float scale = 0.6324555320336759f * rinv * env;
        #pragma unroll
        for (int b = 0; b < 8; b++)
            rbl[tid * 8 + b] = scale * __sinf((float)(b + 1) * PI * rc);
    }
    __syncthreads();

    // ---- hs fill: hsl[m][c] = bf16(node_embed[sp_m][c]) ----
    {
        int m = tid >> 2, c0 = (tid & 3) * 16;
        const float* hr = node_embed + spl[m] * 64 + c0;
        #pragma unroll
        for (int i = 0; i < 16; i++) hsl[m * 64 + c0 + i] = bf16u(hr[i]);
    }

    // ---- stage 1 (VALU, K=8): hid1[m][j] = silu(rb . w1[:,j]) -> a2l bf16 ----
    {
        int m = tid & 63, jg = tid >> 6;
        float r0 = rbl[m * 8 + 0], r1 = rbl[m * 8 + 1], r2 = rbl[m * 8 + 2], r3 = rbl[m * 8 + 3];
        float r4 = rbl[m * 8 + 4], r5 = rbl[m * 8 + 5], r6 = rbl[m * 8 + 6], r7 = rbl[m * 8 + 7];
        #pragma unroll
        for (int jp = 0; jp < 8; jp++) {
            int j = jg * 16 + jp * 2;
            float h0 = silu_f(r0 * w1[j]       + r1 * w1[64 + j]  + r2 * w1[128 + j] + r3 * w1[192 + j]
                            + r4 * w1[256 + j] + r5 * w1[320 + j] + r6 * w1[384 + j] + r7 * w1[448 + j]);
            float h1 = silu_f(r0 * w1[j + 1]     + r1 * w1[64 + j + 1]  + r2 * w1[128 + j + 1] + r3 * w1[192 + j + 1]
                            + r4 * w1[256 + j + 1] + r5 * w1[320 + j + 1] + r6 * w1[384 + j + 1] + r7 * w1[448 + j + 1]);
            *reinterpret_cast<unsigned*>(a2l + swz(m, j * 2)) = pk_bf16(h0, h1);
        }
    }
    __syncthreads();

    // ---- stage 2 MFMA: hid2 = silu(hid1 @ w2), M=64 K=64 N=64 ----
    int w = tid >> 6, l = tid & 63;
    int lrow = l & 15;
    int lkb = (l >> 4) * 16;          // k-group byte offset within 64B k-half
    {
        bf16x8 aF0 = ld_frag(a2l, 16 * w + lrow, lkb);
        bf16x8 aF1 = ld_frag(a2l, 16 * w + lrow, 64 + lkb);
        f32x4 acc[4];
        #pragma unroll
        for (int nt = 0; nt < 4; nt++) {
            f32x4 c = {0.f, 0.f, 0.f, 0.f};
            bf16x8 b0 = ld_frag(w2l, nt * 16 + lrow, lkb);
            bf16x8 b1 = ld_frag(w2l, nt * 16 + lrow, 64 + lkb);
            c = __builtin_amdgcn_mfma_f32_16x16x32_bf16(aF0, b0, c, 0, 0, 0);
            c = __builtin_amdgcn_mfma_f32_16x16x32_bf16(aF1, b1, c, 0, 0, 0);
            acc[nt] = c;
        }
        __syncthreads();   // all reads of a2l complete before overwrite
        #pragma unroll
        for (int nt = 0; nt < 4; nt++) {
            int n = nt * 16 + (l & 15);
            #pragma unroll
            for (int r = 0; r < 4; r++) {
                int m = 16 * w + (l >> 4) * 4 + r;
                *reinterpret_cast<unsigned short*>(a2l + swz(m, n * 2)) = bf16u(silu_f(acc[nt][r]));
            }
        }
    }
    __syncthreads();

    // ---- stage 3 MFMA: wts = hid2 @ w3, M=64 K=64 N=192; epilogue *hs*0.25 ----
    {
        bf16x8 a30 = ld_frag(a2l, 16 * w + lrow, lkb);
        bf16x8 a31 = ld_frag(a2l, 16 * w + lrow, 64 + lkb);
        #pragma unroll
        for (int nt = 0; nt < 12; nt++) {
            f32x4 c = {0.f, 0.f, 0.f, 0.f};
            bf16x8 b0 = ld_frag(w3l, nt * 16 + lrow, lkb);
            bf16x8 b1 = ld_frag(w3l, nt * 16 + lrow, 64 + lkb);
            c = __builtin_amdgcn_mfma_f32_16x16x32_bf16(a30, b0, c, 0, 0, 0);
            c = __builtin_amdgcn_mfma_f32_16x16x32_bf16(a31, b1, c, 0, 0, 0);
            int o = nt * 16 + (l & 15);
            #pragma unroll
            for (int r = 0; r < 4; r++) {
                int m = 16 * w + (l >> 4) * 4 + r;
                float hsf = __uint_as_float(((unsigned)hsl[m * 64 + (o & 63)]) << 16);
                otl[m * 200 + o] = bf16u(c[r] * hsf * 0.25f);
            }
        }
    }
    __syncthreads();

    // ---- coalesced copy: out tile rows -> payload rows at CSR slots ----
    {
        const uint4* ot4 = reinterpret_cast<const uint4*>(otl);
        uint4* pay4 = reinterpret_cast<uint4*>(payload);
        for (int i = tid; i < 64 * 25; i += 256) {
            int row = i / 25, q = i - row * 25;
            pay4[(size_t)slotl[row] * 25 + q] = ot4[row * 25 + q];
        }
    }
}

// ---- fused gather + node stage + focus/species heads: one wave per node ----
__global__ __launch_bounds__(256, 4) void node_kernel(
    const unsigned* __restrict__ payload, const int* __restrict__ start,
    const int* __restrict__ species, const float* __restrict__ node_embed,
    const float* __restrict__ lin_w0, const float* __restrict__ lin_w1,
    const float* __restrict__ lin_w2, const float* __restrict__ skip_w,
    const float* __restrict__ gate_w, const float* __restrict__ focus_w,
    const float* __restrict__ focus_b, const int* __restrict__ flags,
    const float* __restrict__ species_w, const float* __restrict__ species_b,
    float* __restrict__ out_focus, float* __restrict__ out_species,
    float* __restrict__ focus_emb)
{
    int wave = threadIdx.x >> 6;
    int lane = threadIdx.x & 63;
    int n = blockIdx.x * 4 + wave;

    __shared__ float sa[4][9][64];
    __shared__ float hh[4][64];
    __shared__ float ss[4][64];

    float a0 = 0, a1x = 0, a1y = 0, a1z = 0;
    float a2a = 0, a2b = 0, a2c = 0, a2d = 0, a2e = 0;
    float c0 = 0, c1x = 0, c1y = 0, c1z = 0;
    float c2a = 0, c2b = 0, c2c = 0, c2d = 0, c2e = 0;
    int s0 = start[n], s1 = start[n + 1];
    int i = s0;
    for (; i + 1 < s1; i += 2) {
        const unsigned short* pA = (const unsigned short*)(payload + (size_t)i * (PAYL / 2));
        const unsigned short* pB = (const unsigned short*)(payload + (size_t)(i + 1) * (PAYL / 2));
        float Ab0 = __uint_as_float(((unsigned)pA[lane]) << 16);
        float Ab1 = __uint_as_float(((unsigned)pA[64 + lane]) << 16);
        float Ab2 = __uint_as_float(((unsigned)pA[128 + lane]) << 16);
        uint4 Asv = *reinterpret_cast<const uint4*>(pA + 192);
        float Bb0 = __uint_as_float(((unsigned)pB[lane]) << 16);
        float Bb1 = __uint_as_float(((unsigned)pB[64 + lane]) << 16);
        float Bb2 = __uint_as_float(((unsigned)pB[128 + lane]) << 16);
        uint4 Bsv = *reinterpret_cast<const uint4*>(pB + 192);
        a0  += Ab0;
        a1x += Ab1 * bf_lo(Asv.x); a1y += Ab1 * bf_hi(Asv.x); a1z += Ab1 * bf_lo(Asv.y);
        a2a += Ab2 * bf_hi(Asv.y); a2b += Ab2 * bf_lo(Asv.z); a2c += Ab2 * bf_hi(Asv.z);
        a2d += Ab2 * bf_lo(Asv.w); a2e += Ab2 * bf_hi(Asv.w);
        c0  += Bb0;
        c1x += Bb1 * bf_lo(Bsv.x); c1y += Bb1 * bf_hi(Bsv.x); c1z += Bb1 * bf_lo(Bsv.y);
        c2a += Bb2 * bf_hi(Bsv.y); c2b += Bb2 * bf_lo(Bsv.z); c2c += Bb2 * bf_hi(Bsv.z);
        c2d += Bb2 * bf_lo(Bsv.w); c2e += Bb2 * bf_hi(Bsv.w);
    }
    if (i < s1) {
        const unsigned short* pA = (const unsigned short*)(payload + (size_t)i * (PAYL / 2));
        float Ab0 = __uint_as_float(((unsigned)pA[lane]) << 16);
        float Ab1 = __uint_as_float(((unsigned)pA[64 + lane]) << 16);
        float Ab2 = __uint_as_float(((unsigned)pA[128 + lane]) << 16);
        uint4 Asv = *reinterpret_cast<const uint4*>(pA + 192);
        a0  += Ab0;
        a1x += Ab1 * bf_lo(Asv.x); a1y += Ab1 * bf_hi(Asv.x); a1z += Ab1 * bf_lo(Asv.y);
        a2a += Ab2 * bf_hi(Asv.y); a2b += Ab2 * bf_lo(Asv.z); a2c += Ab2 * bf_hi(Asv.z);
        a2d += Ab2 * bf_lo(Asv.w); a2e += Ab2 * bf_hi(Asv.w);
    }
    a0 += c0; a1x += c1x; a1y += c1y; a1z += c1z;
    a2a += c2a; a2b += c2b; a2c += c2c; a2d += c2d; a2e += c2e;

    sa[wave][0][lane] = a0;
    sa[wave][1][lane] = a1x; sa[wave][2][lane] = a1y; sa[wave][3][lane] = a1z;
    sa[wave][4][lane] = a2a; sa[wave][5][lane] = a2b; sa[wave][6][lane] = a2c;
    sa[wave][7][lane] = a2d; sa[wave][8][lane] = a2e;
    int spn = species[n];
    hh[wave][lane] = node_embed[spn * 64 + lane];

    float s = 0.0f;
    const float* skipb = skip_w + spn * 4096;
    #pragma unroll 4
    for (int c = 0; c < 64; c++)
        s += sa[wave][0][c] * lin_w0[c * 64 + lane] + hh[wave][c] * skipb[c * 64 + lane];

    float v0 = 0, v1 = 0, v2 = 0, t0 = 0, t1 = 0, t2 = 0, t3 = 0, t4 = 0;
    #pragma unroll 4
    for (int c = 0; c < 64; c++) {
        float wa = lin_w1[c * 64 + lane];
        v0 += sa[wave][1][c] * wa; v1 += sa[wave][2][c] * wa; v2 += sa[wave][3][c] * wa;
        float wb = lin_w2[c * 64 + lane];
        t0 += sa[wave][4][c] * wb; t1 += sa[wave][5][c] * wb; t2 += sa[wave][6][c] * wb;
        t3 += sa[wave][7][c] * wb; t4 += sa[wave][8][c] * wb;
    }

    ss[wave][lane] = s;
    float g1a = 0.0f, g2a = 0.0f;
    #pragma unroll 4
    for (int c = 0; c < 64; c++) {
        float sc = ss[wave][c];
        g1a += sc * gate_w[c * 128 + lane];
        g2a += sc * gate_w[c * 128 + 64 + lane];
    }
    float g1 = sigm_f(g1a), g2 = sigm_f(g2a);
    float s_out = s * sigm_f(s);
    float vo0 = v0 * g1, vo1 = v1 * g1, vo2 = v2 * g1;
    float to0 = t0 * g2, to1 = t1 * g2, to2 = t2 * g2, to3 = t3 * g2, to4 = t4 * g2;

    float pfo = s_out * focus_w[lane]
              + vo0 * focus_w[64 + lane * 3 + 0]
              + vo1 * focus_w[64 + lane * 3 + 1]
              + vo2 * focus_w[64 + lane * 3 + 2]
              + to0 * focus_w[256 + lane * 5 + 0]
              + to1 * focus_w[256 + lane * 5 + 1]
              + to2 * focus_w[256 + lane * 5 + 2]
              + to3 * focus_w[256 + lane * 5 + 3]
              + to4 * focus_w[256 + lane * 5 + 4];
    #pragma unroll
    for (int off = 32; off > 0; off >>= 1) pfo += __shfl_down(pfo, off);
    if (lane == 0) out_focus[n] = pfo + focus_b[0];

    int fg = flags[n];
    if (fg) {
        float* fe = focus_emb + (size_t)(fg - 1) * FLATDIM;
        fe[lane] = s_out;
        fe[64 + lane * 3 + 0] = vo0;
        fe[64 + lane * 3 + 1] = vo1;
        fe[64 + lane * 3 + 2] = vo2;
        fe[256 + lane * 5 + 0] = to0;
        fe[256 + lane * 5 + 1] = to1;
        fe[256 + lane * 5 + 2] = to2;
        fe[256 + lane * 5 + 3] = to3;
        fe[256 + lane * 5 + 4] = to4;

        // species head: 5 logits via wave reduction (emb is distributed over lanes)
        #pragma unroll
        for (int j = 0; j < 5; j++) {
            float acc = s_out * species_w[lane * 5 + j]
                      + vo0 * species_w[(64 + lane * 3 + 0) * 5 + j]
                      + vo1 * species_w[(64 + lane * 3 + 1) * 5 + j]
                      + vo2 * species_w[(64 + lane * 3 + 2) * 5 + j]
                      + to0 * species_w[(256 + lane * 5 + 0) * 5 + j]
                      + to1 * species_w[(256 + lane * 5 + 1) * 5 + j]
                      + to2 * species_w[(256 + lane * 5 + 2) * 5 + j]
                      + to3 * species_w[(256 + lane * 5 + 3) * 5 + j]
                      + to4 * species_w[(256 + lane * 5 + 4) * 5 + j];
            #pragma unroll
            for (int off = 32; off > 0; off >>= 1) acc += __shfl_down(acc, off);
            if (lane == 0) out_species[(fg - 1) * 5 + j] = acc + species_b[j];
        }
    }
}

// ---- pos head: grid = 100 graphs x 4 k-splits; bf16 weights; atomicAdd combine ----
__global__ __launch_bounds__(256) void pos_kernel(
    const float* __restrict__ focus_emb, const int* __restrict__ target_species,
    const float* __restrict__ species_embed,
    const unsigned* __restrict__ posw_bf, const float* __restrict__ pos_b,
    float* __restrict__ out_pos)
{
    int g  = blockIdx.x >> 2;
    int ks = blockIdx.x & 3;
    int k0 = ks * 160;
    int tid = threadIdx.x;
    __shared__ float pin[160];

    if (tid < 160) {
        int k = k0 + tid;
        pin[tid] = (k < FLATDIM) ? focus_emb[(size_t)g * FLATDIM + k]
                                 : species_embed[target_species[g] * CC + (k - FLATDIM)];
    }
    __syncthreads();

    if (tid < 200) {
        float a0 = 0, a1 = 0, a2 = 0, a3 = 0, a4 = 0, a5 = 0, a6 = 0, a7 = 0;
        const unsigned* wp = posw_bf + (size_t)k0 * 800 + tid * 4;
        #pragma unroll 4
        for (int kk = 0; kk < 160; kk++) {
            uint4 wv = *reinterpret_cast<const uint4*>(wp + (size_t)kk * 800);
            float p = pin[kk];
            a0 += p * bf_lo(wv.x); a1 += p * bf_hi(wv.x);
            a2 += p * bf_lo(wv.y); a3 += p * bf_hi(wv.y);
            a4 += p * bf_lo(wv.z); a5 += p * bf_hi(wv.z);
            a6 += p * bf_lo(wv.w); a7 += p * bf_hi(wv.w);
        }
        float* op = out_pos + (size_t)g * POSOUT + tid * 8;
        if (ks == 0) {
            const float* bb = pos_b + tid * 8;
            atomicAdd(op + 0, a0 + bb[0]); atomicAdd(op + 1, a1 + bb[1]);
            atomicAdd(op + 2, a2 + bb[2]); atomicAdd(op + 3, a3 + bb[3]);
            atomicAdd(op + 4, a4 + bb[4]); atomicAdd(op + 5, a5 + bb[5]);
            atomicAdd(op + 6, a6 + bb[6]); atomicAdd(op + 7, a7 + bb[7]);
        } else {
            atomicAdd(op + 0, a0); atomicAdd(op + 1, a1);
            atomicAdd(op + 2, a2); atomicAdd(op + 3, a3);
            atomicAdd(op + 4, a4); atomicAdd(op + 5, a5);
            atomicAdd(op + 6, a6); atomicAdd(op + 7, a7);
        }
    }
}

extern "C" void kernel_launch(void* const* d_in, const int* in_sizes, int n_in,
                              void* d_out, int out_size, void* d_ws, size_t ws_size,
                              hipStream_t stream) {
    const float* positions      = (const float*)d_in[0];
    const int*   species        = (const int*)  d_in[1];
    const int*   senders        = (const int*)  d_in[2];
    const int*   receivers      = (const int*)  d_in[3];
    const int*   n_node         = (const int*)  d_in[4];
    const int*   target_species = (const int*)  d_in[5];
    const float* species_embed  = (const float*)d_in[6];
    const float* node_embed     = (const float*)d_in[7];
    const float* radial_w1      = (const float*)d_in[8];
    const float* radial_w2      = (const float*)d_in[9];
    const float* radial_w3      = (const float*)d_in[10];
    const float* lin_w0         = (const float*)d_in[11];
    const float* lin_w1         = (const float*)d_in[12];
    const float* lin_w2         = (const float*)d_in[13];
    const float* skip_w         = (const float*)d_in[14];
    const float* gate_w         = (const float*)d_in[15];
    const float* focus_w        = (const float*)d_in[16];
    const float* focus_b        = (const float*)d_in[17];
    const float* species_w      = (const float*)d_in[18];
    const float* species_b      = (const float*)d_in[19];
    const float* pos_w          = (const float*)d_in[20];
    const float* pos_b          = (const float*)d_in[21];

    // ws layout (16B-aligned chunks first):
    //   payload [320000*100 u32 = 128MB]
    // | posw_bf [640*800 u32 = 2MB]
    // | degree[20000] cursor[20000] flags[20000] start[20001] (ints)
    // | w2tn_g[2048 u32] w3tn_g[6144 u32] | focus_emb[57600 f32]
    unsigned* payload = (unsigned*)d_ws;
    unsigned* posw_bf = payload + (size_t)NEDGES * (PAYL / 2);
    int* degree = (int*)(posw_bf + 640 * 800);
    int* cursor = degree + NNODES;
    int* flags  = cursor + NNODES;
    int* start  = flags + NNODES;
    unsigned* w2tn_g = (unsigned*)(start + NNODES + 1);
    unsigned* w3tn_g = w2tn_g + 2048;
    float* focus_emb = (float*)(w3tn_g + 6144);

    float* out       = (float*)d_out;
    float* out_focus = out;
    float* out_spec  = out + NNODES;
    float* out_pos   = out + NNODES + NGRAPHS * 5;

    hipMemsetAsync(degree, 0, 3 * NNODES * sizeof(int), stream);
    hipMemsetAsync(out_pos, 0, (size_t)NGRAPHS * POSOUT * sizeof(float), stream);

    prep_kernel<<<128, 256, 0, stream>>>(radial_w2, radial_w3, pos_w, n_node, receivers,
                                         w2tn_g, w3tn_g, posw_bf, flags, degree);
    scan_kernel<<<1, 1024, 0, stream>>>(degree, start);
    edge_kernel<<<NEDGES / 64, 256, 0, stream>>>(
        positions, species, senders, receivers, node_embed, radial_w1,
        w2tn_g, w3tn_g, start, cursor, payload);

    node_kernel<<<NNODES / 4, 256, 0, stream>>>(
        payload, start, species, node_embed,
        lin_w0, lin_w1, lin_w2, skip_w, gate_w, focus_w, focus_b, flags,
        species_w, species_b, out_focus, out_spec, focus_emb);

    pos_kernel<<<NGRAPHS * 4, 256, 0, stream>>>(
        focus_emb, target_species, species_embed, posw_bf, pos_b, out_pos);
}

// Round 8
// 253.729 us; speedup vs baseline: 3.2700x; 1.0167x over previous
//
#include <hip/hip_runtime.h>
#include <hip/hip_bf16.h>
#include <math.h>

// ---- problem constants ----
#define NNODES   20000
#define NEDGES   320000
#define NGRAPHS  100
#define CC       64        // LATENT
#define FLATDIM  576       // C*(1+3+5)
#define POSIN    640       // FLAT + C
#define POSOUT   1600      // NRADII*IRRDIM
#define PAYL     200       // bf16 row: b0[64] b1[64] b2[64] sh[8] -> 400B (25 uint4)

typedef __attribute__((ext_vector_type(8))) short bf16x8;
typedef __attribute__((ext_vector_type(4))) float f32x4;

__device__ __forceinline__ float silu_f(float x){ return x / (1.0f + __expf(-x)); }
__device__ __forceinline__ float sigm_f(float x){ return 1.0f / (1.0f + __expf(-x)); }
__device__ __forceinline__ unsigned pk_bf16(float lo, float hi){
    __hip_bfloat162 t;
    t.x = __float2bfloat16(lo);
    t.y = __float2bfloat16(hi);
    return *reinterpret_cast<unsigned*>(&t);
}
__device__ __forceinline__ unsigned short bf16u(float x){
    __hip_bfloat16 h = __float2bfloat16(x);
    return *reinterpret_cast<unsigned short*>(&h);
}
__device__ __forceinline__ float bf_lo(unsigned u){ return __uint_as_float(u << 16); }
__device__ __forceinline__ float bf_hi(unsigned u){ return __uint_as_float(u & 0xffff0000u); }

// ---- prep: w2/w3 n-major bf16 pairs (0.25 folded into w3); pos_w bf16; flags; degree ----
__global__ void prep_kernel(const float* __restrict__ w2, const float* __restrict__ w3,
                            const float* __restrict__ pos_w,
                            const int* __restrict__ n_node,
                            const int* __restrict__ receivers,
                            unsigned* __restrict__ w2tn_g, unsigned* __restrict__ w3tn_g,
                            unsigned* __restrict__ posw_bf,
                            int* __restrict__ flags, int* __restrict__ degree)
{
    int tid = blockIdx.x * blockDim.x + threadIdx.x;
    int stride = gridDim.x * blockDim.x;
    for (int i = tid; i < 2048; i += stride) {          // w2: 64n x 32 k-pairs
        int n = i >> 5, k = (i & 31) * 2;
        w2tn_g[i] = pk_bf16(w2[k * 64 + n], w2[(k + 1) * 64 + n]);
    }
    for (int i = tid; i < 6144; i += stride) {          // w3: 192o x 32 k-pairs, x0.25
        int o = i >> 5, k = (i & 31) * 2;
        w3tn_g[i] = pk_bf16(w3[k * 192 + o] * 0.25f, w3[(k + 1) * 192 + o] * 0.25f);
    }
    for (int i = tid; i < 640 * 800; i += stride) {     // pos_w: [640][800 o-pairs]
        int k = i / 800, o = (i - k * 800) * 2;
        posw_bf[i] = pk_bf16(pos_w[(size_t)k * 1600 + o], pos_w[(size_t)k * 1600 + o + 1]);
    }
    for (int e = tid; e < NEDGES; e += stride)
        atomicAdd(&degree[receivers[e]], 1);
    if (tid == 0) {
        int a = 0;
        for (int g = 0; g < NGRAPHS; g++) { flags[a] = g + 1; a += n_node[g]; }
    }
}

// ---- exclusive scan of degree[20000] -> start[20001], single block ----
__global__ __launch_bounds__(1024) void scan_kernel(const int* __restrict__ degree,
                                                    int* __restrict__ start)
{
    __shared__ int partial[1024];
    int t = threadIdx.x;
    int base = t * 20;
    int s = 0;
    int loc[20];
    for (int i = 0; i < 20; i++) {
        int idx = base + i;
        int d = (idx < NNODES) ? degree[idx] : 0;
        loc[i] = s;
        s += d;
    }
    partial[t] = s;
    __syncthreads();
    if (t == 0) {
        int run = 0;
        for (int i = 0; i < 1024; i++) { int x = partial[i]; partial[i] = run; run += x; }
        start[NNODES] = run;
    }
    __syncthreads();
    int off = partial[t];
    for (int i = 0; i < 20; i++) {
        int idx = base + i;
        if (idx < NNODES) start[idx] = off + loc[i];
    }
}

// swizzled LDS byte offset for [row][128B] tiles: XOR row bits into 16B-slot bits (G4)
__device__ __forceinline__ int swz(int row, int kbyte){
    return row * 128 + (kbyte ^ ((row & 7) << 4));
}
__device__ __forceinline__ bf16x8 ld_frag(const unsigned char* base, int row, int kbyte){
    return *reinterpret_cast<const bf16x8*>(base + swz(row, kbyte));
}
__device__ __forceinline__ bf16x8 ld_gfrag(const unsigned* base, int row, int kchunk){
    return *reinterpret_cast<const bf16x8*>(base + row * 32 + kchunk * 4);
}

// ---- edge stage: MFMA, no weight LDS staging, hs deferred to node ----
__global__ __launch_bounds__(256, 4) void edge_kernel(
    const float* __restrict__ pos, const int* __restrict__ species,
    const int* __restrict__ senders, const int* __restrict__ receivers,
    const float* __restrict__ w1,
    const unsigned* __restrict__ w2tn_g, const unsigned* __restrict__ w3tn_g,
    const int* __restrict__ start, int* __restrict__ cursor,
    unsigned* __restrict__ payload, int* __restrict__ spbuf)
{
    __shared__ __align__(16) unsigned char a2l[8192];      // hid1 then hid2, swizzled
    __shared__ __align__(16) unsigned short otl[64 * PAYL]; // out tile (payload rows)
    __shared__ float rbl[64 * 8];
    __shared__ int slotl[64];

    int tid = threadIdx.x;
    int w = tid >> 6, l = tid & 63;
    int lrow = l & 15;
    int kh = l >> 4;           // k-half-chunk 0..3
    int lkb = kh * 16;         // byte offset within 64B k-half

    // prefetch stage-2 B frags from global (registers; overlaps phase A)
    bf16x8 w2b0[4], w2b1[4];
    #pragma unroll
    for (int nt = 0; nt < 4; nt++) {
        w2b0[nt] = ld_gfrag(w2tn_g, nt * 16 + lrow, kh);
        w2b1[nt] = ld_gfrag(w2tn_g, nt * 16 + lrow, 4 + kh);
    }

    // ---- phase A: per-edge geometry + CSR slot (one thread per edge) ----
    if (tid < 64) {
        int e = blockIdx.x * 64 + tid;
        int snd = senders[e];
        int rcv = receivers[e];
        int slot = start[rcv] + atomicAdd(&cursor[rcv], 1);
        slotl[tid] = slot;
        spbuf[slot] = species[snd];

        float dx = pos[rcv * 3 + 0] - pos[snd * 3 + 0];
        float dy = pos[rcv * 3 + 1] - pos[snd * 3 + 1];
        float dz = pos[rcv * 3 + 2] - pos[snd * 3 + 2];
        float r = sqrtf(dx * dx + dy * dy + dz * dz);
        float rinv = 1.0f / (r + 1e-9f);
        float ux = dx * rinv, uy = dy * rinv, uz = dz * rinv;

        const float SQ3 = 1.7320508075688772f;
        const float S15 = 3.872983346207417f;
        const float S5  = 2.2360679774997896f;
        otl[tid * PAYL + 192] = bf16u(SQ3 * ux);
        otl[tid * PAYL + 193] = bf16u(SQ3 * uy);
        otl[tid * PAYL + 194] = bf16u(SQ3 * uz);
        otl[tid * PAYL + 195] = bf16u(S15 * ux * uy);
        otl[tid * PAYL + 196] = bf16u(S15 * uy * uz);
        otl[tid * PAYL + 197] = bf16u(0.5f * S5 * (3.0f * uz * uz - 1.0f));
        otl[tid * PAYL + 198] = bf16u(S15 * ux * uz);
        otl[tid * PAYL + 199] = bf16u(0.5f * S15 * (ux * ux - uy * uy));

        const float PI = 3.14159265358979323846f;
        float rc = r * 0.2f;
        float env = 0.5f * (__cosf(PI * fminf(rc, 1.0f)) + 1.0f);
        float scale = 0.6324555320336759f * rinv * env;
        #pragma unroll
        for (int b = 0; b < 8; b++)
            rbl[tid * 8 + b] = scale * __sinf((float)(b + 1) * PI * rc);
    }
    __syncthreads();

    // ---- stage 1 (VALU, K=8): hid1[m][j] = silu(rb . w1[:,j]) -> a2l bf16 ----
    {
        int m = tid & 63;
        float r0 = rbl[m * 8 + 0], r1 = rbl[m * 8 + 1], r2 = rbl[m * 8 + 2], r3 = rbl[m * 8 + 3];
        float r4 = rbl[m * 8 + 4], r5 = rbl[m * 8 + 5], r6 = rbl[m * 8 + 6], r7 = rbl[m * 8 + 7];
        #pragma unroll
        for (int jp = 0; jp < 8; jp++) {
            int j = w * 16 + jp * 2;    // wave-uniform column -> scalar w1 loads
            float h0 = silu_f(r0 * w1[j]       + r1 * w1[64 + j]  + r2 * w1[128 + j] + r3 * w1[192 + j]
                            + r4 * w1[256 + j] + r5 * w1[320 + j] + r6 * w1[384 + j] + r7 * w1[448 + j]);
            float h1 = silu_f(r0 * w1[j + 1]     + r1 * w1[64 + j + 1]  + r2 * w1[128 + j + 1] + r3 * w1[192 + j + 1]
                            + r4 * w1[256 + j + 1] + r5 * w1[320 + j + 1] + r6 * w1[384 + j + 1] + r7 * w1[448 + j + 1]);
            *reinterpret_cast<unsigned*>(a2l + swz(m, j * 2)) = pk_bf16(h0, h1);
        }
    }
    __syncthreads();

    // ---- stage 2 MFMA: hid2 = silu(hid1 @ w2), M=64 K=64 N=64 ----
    {
        bf16x8 aF0 = ld_frag(a2l, 16 * w + lrow, lkb);
        bf16x8 aF1 = ld_frag(a2l, 16 * w + lrow, 64 + lkb);
        f32x4 acc[4];
        #pragma unroll
        for (int nt = 0; nt < 4; nt++) {
            f32x4 c = {0.f, 0.f, 0.f, 0.f};
            c = __builtin_amdgcn_mfma_f32_16x16x32_bf16(aF0, w2b0[nt], c, 0, 0, 0);
            c = __builtin_amdgcn_mfma_f32_16x16x32_bf16(aF1, w2b1[nt], c, 0, 0, 0);
            acc[nt] = c;
        }
        __syncthreads();   // all reads of a2l complete before overwrite
        #pragma unroll
        for (int nt = 0; nt < 4; nt++) {
            int n = nt * 16 + lrow;
            #pragma unroll
            for (int r = 0; r < 4; r++) {
                int m = 16 * w + kh * 4 + r;
                *reinterpret_cast<unsigned short*>(a2l + swz(m, n * 2)) = bf16u(silu_f(acc[nt][r]));
            }
        }
    }
    __syncthreads();

    // ---- stage 3 MFMA: wts*0.25 = hid2 @ w3q, wave owns 3 output nt-groups ----
    {
        bf16x8 w3b0[3], w3b1[3];
        #pragma unroll
        for (int nl = 0; nl < 3; nl++) {
            int o16 = (3 * w + nl) * 16 + lrow;
            w3b0[nl] = ld_gfrag(w3tn_g, o16, kh);
            w3b1[nl] = ld_gfrag(w3tn_g, o16, 4 + kh);
        }
        #pragma unroll
        for (int mt = 0; mt < 4; mt++) {
            bf16x8 a30 = ld_frag(a2l, 16 * mt + lrow, lkb);
            bf16x8 a31 = ld_frag(a2l, 16 * mt + lrow, 64 + lkb);
            #pragma unroll
            for (int nl = 0; nl < 3; nl++) {
                f32x4 c = {0.f, 0.f, 0.f, 0.f};
                c = __builtin_amdgcn_mfma_f32_16x16x32_bf16(a30, w3b0[nl], c, 0, 0, 0);
                c = __builtin_amdgcn_mfma_f32_16x16x32_bf16(a31, w3b1[nl], c, 0, 0, 0);
                int o = (3 * w + nl) * 16 + lrow;
                #pragma unroll
                for (int r = 0; r < 4; r++) {
                    int m = 16 * mt + kh * 4 + r;
                    otl[m * PAYL + o] = bf16u(c[r]);
                }
            }
        }
    }
    __syncthreads();

    // ---- coalesced copy: out tile rows -> payload rows at CSR slots ----
    {
        const uint4* ot4 = reinterpret_cast<const uint4*>(otl);
        uint4* pay4 = reinterpret_cast<uint4*>(payload);
        for (int i = tid; i < 64 * 25; i += 256) {
            int row = i / 25, q = i - row * 25;
            pay4[(size_t)slotl[row] * 25 + q] = ot4[row * 25 + q];
        }
    }
}

// ---- fused gather + node stage + focus/species heads: one wave per node ----
__global__ __launch_bounds__(256, 4) void node_kernel(
    const unsigned* __restrict__ payload, const int* __restrict__ spbuf,
    const int* __restrict__ start,
    const int* __restrict__ species, const float* __restrict__ node_embed,
    const float* __restrict__ lin_w0, const float* __restrict__ lin_w1,
    const float* __restrict__ lin_w2, const float* __restrict__ skip_w,
    const float* __restrict__ gate_w, const float* __restrict__ focus_w,
    const float* __restrict__ focus_b, const int* __restrict__ flags,
    const float* __restrict__ species_w, const float* __restrict__ species_b,
    float* __restrict__ out_focus, float* __restrict__ out_species,
    float* __restrict__ focus_emb)
{
    int wave = threadIdx.x >> 6;
    int lane = threadIdx.x & 63;
    int n = blockIdx.x * 4 + wave;

    __shared__ float sa[4][9][64];
    __shared__ float hh[4][64];
    __shared__ float ss[4][64];

    float a0 = 0, a1x = 0, a1y = 0, a1z = 0;
    float a2a = 0, a2b = 0, a2c = 0, a2d = 0, a2e = 0;
    float c0 = 0, c1x = 0, c1y = 0, c1z = 0;
    float c2a = 0, c2b = 0, c2c = 0, c2d = 0, c2e = 0;
    int s0 = start[n], s1 = start[n + 1];
    int i = s0;
    for (; i + 1 < s1; i += 2) {
        const unsigned short* pA = (const unsigned short*)(payload + (size_t)i * (PAYL / 2));
        const unsigned short* pB = (const unsigned short*)(payload + (size_t)(i + 1) * (PAYL / 2));
        float hsA = node_embed[spbuf[i] * 64 + lane];
        float hsB = node_embed[spbuf[i + 1] * 64 + lane];
        float Ab0 = __uint_as_float(((unsigned)pA[lane]) << 16) * hsA;
        float Ab1 = __uint_as_float(((unsigned)pA[64 + lane]) << 16) * hsA;
        float Ab2 = __uint_as_float(((unsigned)pA[128 + lane]) << 16) * hsA;
        uint4 Asv = *reinterpret_cast<const uint4*>(pA + 192);
        float Bb0 = __uint_as_float(((unsigned)pB[lane]) << 16) * hsB;
        float Bb1 = __uint_as_float(((unsigned)pB[64 + lane]) << 16) * hsB;
        float Bb2 = __uint_as_float(((unsigned)pB[128 + lane]) << 16) * hsB;
        uint4 Bsv = *reinterpret_cast<const uint4*>(pB + 192);
        a0  += Ab0;
        a1x += Ab1 * bf_lo(Asv.x); a1y += Ab1 * bf_hi(Asv.x); a1z += Ab1 * bf_lo(Asv.y);
        a2a += Ab2 * bf_hi(Asv.y); a2b += Ab2 * bf_lo(Asv.z); a2c += Ab2 * bf_hi(Asv.z);
        a2d += Ab2 * bf_lo(Asv.w); a2e += Ab2 * bf_hi(Asv.w);
        c0  += Bb0;
        c1x += Bb1 * bf_lo(Bsv.x); c1y += Bb1 * bf_hi(Bsv.x); c1z += Bb1 * bf_lo(Bsv.y);
        c2a += Bb2 * bf_hi(Bsv.y); c2b += Bb2 * bf_lo(Bsv.z); c2c += Bb2 * bf_hi(Bsv.z);
        c2d += Bb2 * bf_lo(Bsv.w); c2e += Bb2 * bf_hi(Bsv.w);
    }
    if (i < s1) {
        const unsigned short* pA = (const unsigned short*)(payload + (size_t)i * (PAYL / 2));
        float hsA = node_embed[spbuf[i] * 64 + lane];
        float Ab0 = __uint_as_float(((unsigned)pA[lane]) << 16) * hsA;
        float Ab1 = __uint_as_float(((unsigned)pA[64 + lane]) << 16) * hsA;
        float Ab2 = __uint_as_float(((unsigned)pA[128 + lane]) << 16) * hsA;
        uint4 Asv = *reinterpret_cast<const uint4*>(pA + 192);
        a0  += Ab0;
        a1x += Ab1 * bf_lo(Asv.x); a1y += Ab1 * bf_hi(Asv.x); a1z += Ab1 * bf_lo(Asv.y);
        a2a += Ab2 * bf_hi(Asv.y); a2b += Ab2 * bf_lo(Asv.z); a2c += Ab2 * bf_hi(Asv.z);
        a2d += Ab2 * bf_lo(Asv.w); a2e += Ab2 * bf_hi(Asv.w);
    }
    a0 += c0; a1x += c1x; a1y += c1y; a1z += c1z;
    a2a += c2a; a2b += c2b; a2c += c2c; a2d += c2d; a2e += c2e;

    sa[wave][0][lane] = a0;
    sa[wave][1][lane] = a1x; sa[wave][2][lane] = a1y; sa[wave][3][lane] = a1z;
    sa[wave][4][lane] = a2a; sa[wave][5][lane] = a2b; sa[wave][6][lane] = a2c;
    sa[wave][7][lane] = a2d; sa[wave][8][lane] = a2e;
    int spn = species[n];
    hh[wave][lane] = node_embed[spn * 64 + lane];

    float s = 0.0f;
    const float* skipb = skip_w + spn * 4096;
    #pragma unroll 4
    for (int c = 0; c < 64; c++)
        s += sa[wave][0][c] * lin_w0[c * 64 + lane] + hh[wave][c] * skipb[c * 64 + lane];

    float v0 = 0, v1 = 0, v2 = 0, t0 = 0, t1 = 0, t2 = 0, t3 = 0, t4 = 0;
    #pragma unroll 4
    for (int c = 0; c < 64; c++) {
        float wa = lin_w1[c * 64 + lane];
        v0 += sa[wave][1][c] * wa; v1 += sa[wave][2][c] * wa; v2 += sa[wave][3][c] * wa;
        float wb = lin_w2[c * 64 + lane];
        t0 += sa[wave][4][c] * wb; t1 += sa[wave][5][c] * wb; t2 += sa[wave][6][c] * wb;
        t3 += sa[wave][7][c] * wb; t4 += sa[wave][8][c] * wb;
    }

    ss[wave][lane] = s;
    float g1a = 0.0f, g2a = 0.0f;
    #pragma unroll 4
    for (int c = 0; c < 64; c++) {
        float sc = ss[wave][c];
        g1a += sc * gate_w[c * 128 + lane];
        g2a += sc * gate_w[c * 128 + 64 + lane];
    }
    float g1 = sigm_f(g1a), g2 = sigm_f(g2a);
    float s_out = s * sigm_f(s);
    float vo0 = v0 * g1, vo1 = v1 * g1, vo2 = v2 * g1;
    float to0 = t0 * g2, to1 = t1 * g2, to2 = t2 * g2, to3 = t3 * g2, to4 = t4 * g2;

    float pfo = s_out * focus_w[lane]
              + vo0 * focus_w[64 + lane * 3 + 0]
              + vo1 * focus_w[64 + lane * 3 + 1]
              + vo2 * focus_w[64 + lane * 3 + 2]
              + to0 * focus_w[256 + lane * 5 + 0]
              + to1 * focus_w[256 + lane * 5 + 1]
              + to2 * focus_w[256 + lane * 5 + 2]
              + to3 * focus_w[256 + lane * 5 + 3]
              + to4 * focus_w[256 + lane * 5 + 4];
    #pragma unroll
    for (int off = 32; off > 0; off >>= 1) pfo += __shfl_down(pfo, off);
    if (lane == 0) out_focus[n] = pfo + focus_b[0];

    int fg = flags[n];
    if (fg) {
        float* fe = focus_emb + (size_t)(fg - 1) * FLATDIM;
        fe[lane] = s_out;
        fe[64 + lane * 3 + 0] = vo0;
        fe[64 + lane * 3 + 1] = vo1;
        fe[64 + lane * 3 + 2] = vo2;
        fe[256 + lane * 5 + 0] = to0;
        fe[256 + lane * 5 + 1] = to1;
        fe[256 + lane * 5 + 2] = to2;
        fe[256 + lane * 5 + 3] = to3;
        fe[256 + lane * 5 + 4] = to4;

        // species head: 5 logits via wave reduction
        #pragma unroll
        for (int j = 0; j < 5; j++) {
            float acc = s_out * species_w[lane * 5 + j]
                      + vo0 * species_w[(64 + lane * 3 + 0) * 5 + j]
                      + vo1 * species_w[(64 + lane * 3 + 1) * 5 + j]
                      + vo2 * species_w[(64 + lane * 3 + 2) * 5 + j]
                      + to0 * species_w[(256 + lane * 5 + 0) * 5 + j]
                      + to1 * species_w[(256 + lane * 5 + 1) * 5 + j]
                      + to2 * species_w[(256 + lane * 5 + 2) * 5 + j]
                      + to3 * species_w[(256 + lane * 5 + 3) * 5 + j]
                      + to4 * species_w[(256 + lane * 5 + 4) * 5 + j];
            #pragma unroll
            for (int off = 32; off > 0; off >>= 1) acc += __shfl_down(acc, off);
            if (lane == 0) out_species[(fg - 1) * 5 + j] = acc + species_b[j];
        }
    }
}

// ---- pos head: grid = 100 graphs x 8 k-splits; bf16 weights; atomicAdd combine ----
__global__ __launch_bounds__(256) void pos_kernel(
    const float* __restrict__ focus_emb, const int* __restrict__ target_species,
    const float* __restrict__ species_embed,
    const unsigned* __restrict__ posw_bf, const float* __restrict__ pos_b,
    float* __restrict__ out_pos)
{
    int g  = blockIdx.x >> 3;
    int ks = blockIdx.x & 7;
    int k0 = ks * 80;
    int tid = threadIdx.x;
    __shared__ float pin[80];

    if (tid < 80) {
        int k = k0 + tid;
        pin[tid] = (k < FLATDIM) ? focus_emb[(size_t)g * FLATDIM + k]
                                 : species_embed[target_species[g] * CC + (k - FLATDIM)];
    }
    __syncthreads();

    if (tid < 200) {
        float a0 = 0, a1 = 0, a2 = 0, a3 = 0, a4 = 0, a5 = 0, a6 = 0, a7 = 0;
        const unsigned* wp = posw_bf + (size_t)k0 * 800 + tid * 4;
        #pragma unroll 4
        for (int kk = 0; kk < 80; kk++) {
            uint4 wv = *reinterpret_cast<const uint4*>(wp + (size_t)kk * 800);
            float p = pin[kk];
            a0 += p * bf_lo(wv.x); a1 += p * bf_hi(wv.x);
            a2 += p * bf_lo(wv.y); a3 += p * bf_hi(wv.y);
            a4 += p * bf_lo(wv.z); a5 += p * bf_hi(wv.z);
            a6 += p * bf_lo(wv.w); a7 += p * bf_hi(wv.w);
        }
        float* op = out_pos + (size_t)g * POSOUT + tid * 8;
        if (ks == 0) {
            const float* bb = pos_b + tid * 8;
            atomicAdd(op + 0, a0 + bb[0]); atomicAdd(op + 1, a1 + bb[1]);
            atomicAdd(op + 2, a2 + bb[2]); atomicAdd(op + 3, a3 + bb[3]);
            atomicAdd(op + 4, a4 + bb[4]); atomicAdd(op + 5, a5 + bb[5]);
            atomicAdd(op + 6, a6 + bb[6]); atomicAdd(op + 7, a7 + bb[7]);
        } else {
            atomicAdd(op + 0, a0); atomicAdd(op + 1, a1);
            atomicAdd(op + 2, a2); atomicAdd(op + 3, a3);
            atomicAdd(op + 4, a4); atomicAdd(op + 5, a5);
            atomicAdd(op + 6, a6); atomicAdd(op + 7, a7);
        }
    }
}

extern "C" void kernel_launch(void* const* d_in, const int* in_sizes, int n_in,
                              void* d_out, int out_size, void* d_ws, size_t ws_size,
                              hipStream_t stream) {
    const float* positions      = (const float*)d_in[0];
    const int*   species        = (const int*)  d_in[1];
    const int*   senders        = (const int*)  d_in[2];
    const int*   receivers      = (const int*)  d_in[3];
    const int*   n_node         = (const int*)  d_in[4];
    const int*   target_species = (const int*)  d_in[5];
    const float* species_embed  = (const float*)d_in[6];
    const float* node_embed     = (const float*)d_in[7];
    const float* radial_w1      = (const float*)d_in[8];
    const float* radial_w2      = (const float*)d_in[9];
    const float* radial_w3      = (const float*)d_in[10];
    const float* lin_w0         = (const float*)d_in[11];
    const float* lin_w1         = (const float*)d_in[12];
    const float* lin_w2         = (const float*)d_in[13];
    const float* skip_w         = (const float*)d_in[14];
    const float* gate_w         = (const float*)d_in[15];
    const float* focus_w        = (const float*)d_in[16];
    const float* focus_b        = (const float*)d_in[17];
    const float* species_w      = (const float*)d_in[18];
    const float* species_b      = (const float*)d_in[19];
    const float* pos_w          = (const float*)d_in[20];
    const float* pos_b          = (const float*)d_in[21];

    // ws layout:
    //   payload [320000*100 u32 = 128MB]
    // | posw_bf [640*800 u32 = 2.05MB]
    // | spbuf   [320000 int = 1.28MB]
    // | degree[20000] cursor[20000] flags[20000] start[20001] (ints)
    // | w2tn_g[2048 u32] w3tn_g[6144 u32] | focus_emb[57600 f32]
    unsigned* payload = (unsigned*)d_ws;
    unsigned* posw_bf = payload + (size_t)NEDGES * (PAYL / 2);
    int* spbuf  = (int*)(posw_bf + 640 * 800);
    int* degree = spbuf + NEDGES;
    int* cursor = degree + NNODES;
    int* flags  = cursor + NNODES;
    int* start  = flags + NNODES;
    unsigned* w2tn_g = (unsigned*)(start + NNODES + 1);
    unsigned* w3tn_g = w2tn_g + 2048;
    float* focus_emb = (float*)(w3tn_g + 6144);

    float* out       = (float*)d_out;
    float* out_focus = out;
    float* out_spec  = out + NNODES;
    float* out_pos   = out + NNODES + NGRAPHS * 5;

    hipMemsetAsync(degree, 0, 3 * NNODES * sizeof(int), stream);
    hipMemsetAsync(out_pos, 0, (size_t)NGRAPHS * POSOUT * sizeof(float), stream);

    prep_kernel<<<256, 256, 0, stream>>>(radial_w2, radial_w3, pos_w, n_node, receivers,
                                         w2tn_g, w3tn_g, posw_bf, flags, degree);
    scan_kernel<<<1, 1024, 0, stream>>>(degree, start);
    edge_kernel<<<NEDGES / 64, 256, 0, stream>>>(
        positions, species, senders, receivers, radial_w1,
        w2tn_g, w3tn_g, start, cursor, payload, spbuf);

    node_kernel<<<NNODES / 4, 256, 0, stream>>>(
        payload, spbuf, start, species, node_embed,
        lin_w0, lin_w1, lin_w2, skip_w, gate_w, focus_w, focus_b, flags,
        species_w, species_b, out_focus, out_spec, focus_emb);

    pos_kernel<<<NGRAPHS * 8, 256, 0, stream>>>(
        focus_emb, target_species, species_embed, posw_bf, pos_b, out_pos);
}

// Round 9
// 251.088 us; speedup vs baseline: 3.3044x; 1.0105x over previous
//
#include <hip/hip_runtime.h>
#include <hip/hip_bf16.h>
#include <math.h>

// ---- problem constants ----
#define NNODES   20000
#define NEDGES   320000
#define NGRAPHS  100
#define CC       64        // LATENT
#define FLATDIM  576       // C*(1+3+5)
#define POSIN    640       // FLAT + C
#define POSOUT   1600      // NRADII*IRRDIM
#define PAYL     200       // bf16 row: b0'[64] b1'[64] b2'[64] sh[8] -> 400B (25 uint4)

typedef __attribute__((ext_vector_type(8))) short bf16x8;
typedef __attribute__((ext_vector_type(4))) float f32x4;

__device__ __forceinline__ float silu_f(float x){ return x / (1.0f + __expf(-x)); }
__device__ __forceinline__ float sigm_f(float x){ return 1.0f / (1.0f + __expf(-x)); }
__device__ __forceinline__ unsigned pk_bf16(float lo, float hi){
    __hip_bfloat162 t;
    t.x = __float2bfloat16(lo);
    t.y = __float2bfloat16(hi);
    return *reinterpret_cast<unsigned*>(&t);
}
__device__ __forceinline__ unsigned short bf16u(float x){
    __hip_bfloat16 h = __float2bfloat16(x);
    return *reinterpret_cast<unsigned short*>(&h);
}
__device__ __forceinline__ float bf_lo(unsigned u){ return __uint_as_float(u << 16); }
__device__ __forceinline__ float bf_hi(unsigned u){ return __uint_as_float(u & 0xffff0000u); }
__device__ __forceinline__ float bfu(unsigned short u){ return __uint_as_float(((unsigned)u) << 16); }

// ---- prep: pack w2/w3 (0.25 in w3) / lin_w0..2 n-major bf16 pairs; pos_w bf16;
//      skip_vec[sp][d]; flags; degree ----
__global__ void prep_kernel(const float* __restrict__ w2, const float* __restrict__ w3,
                            const float* __restrict__ lw0, const float* __restrict__ lw1,
                            const float* __restrict__ lw2,
                            const float* __restrict__ skip_w, const float* __restrict__ node_embed,
                            const float* __restrict__ pos_w,
                            const int* __restrict__ n_node,
                            const int* __restrict__ receivers,
                            unsigned* __restrict__ w2tn_g, unsigned* __restrict__ w3tn_g,
                            unsigned* __restrict__ linp_g, float* __restrict__ skip_vec,
                            unsigned* __restrict__ posw_bf,
                            int* __restrict__ flags, int* __restrict__ degree)
{
    int tid = blockIdx.x * blockDim.x + threadIdx.x;
    int stride = gridDim.x * blockDim.x;
    for (int i = tid; i < 2048; i += stride) {          // w2: 64n x 32 k-pairs
        int n = i >> 5, k = (i & 31) * 2;
        w2tn_g[i] = pk_bf16(w2[k * 64 + n], w2[(k + 1) * 64 + n]);
    }
    for (int i = tid; i < 6144; i += stride) {          // w3: 192o x 32 k-pairs, x0.25
        int o = i >> 5, k = (i & 31) * 2;
        w3tn_g[i] = pk_bf16(w3[k * 192 + o] * 0.25f, w3[(k + 1) * 192 + o] * 0.25f);
    }
    for (int i = tid; i < 3 * 2048; i += stride) {      // lin_wj: [j][64d][32 c-pairs]
        int j = i >> 11, rem = i & 2047;
        int d = rem >> 5, c = (rem & 31) * 2;
        const float* lw = (j == 0) ? lw0 : (j == 1) ? lw1 : lw2;
        linp_g[i] = pk_bf16(lw[c * 64 + d], lw[(c + 1) * 64 + d]);
    }
    for (int i = tid; i < 5 * 64; i += stride) {        // skip_vec[sp][d]
        int sp = i >> 6, d = i & 63;
        float a = 0.0f;
        for (int c = 0; c < 64; c++)
            a += node_embed[sp * 64 + c] * skip_w[(sp * 64 + c) * 64 + d];
        skip_vec[i] = a;
    }
    for (int i = tid; i < 640 * 800; i += stride) {     // pos_w: [640][800 o-pairs]
        int k = i / 800, o = (i - k * 800) * 2;
        posw_bf[i] = pk_bf16(pos_w[(size_t)k * 1600 + o], pos_w[(size_t)k * 1600 + o + 1]);
    }
    for (int e = tid; e < NEDGES; e += stride)
        atomicAdd(&degree[receivers[e]], 1);
    if (tid == 0) {
        int a = 0;
        for (int g = 0; g < NGRAPHS; g++) { flags[a] = g + 1; a += n_node[g]; }
    }
}

// ---- exclusive scan of degree[20000] -> start[20001], single block ----
__global__ __launch_bounds__(1024) void scan_kernel(const int* __restrict__ degree,
                                                    int* __restrict__ start)
{
    __shared__ int partial[1024];
    int t = threadIdx.x;
    int base = t * 20;
    int s = 0;
    int loc[20];
    for (int i = 0; i < 20; i++) {
        int idx = base + i;
        int d = (idx < NNODES) ? degree[idx] : 0;
        loc[i] = s;
        s += d;
    }
    partial[t] = s;
    __syncthreads();
    if (t == 0) {
        int run = 0;
        for (int i = 0; i < 1024; i++) { int x = partial[i]; partial[i] = run; run += x; }
        start[NNODES] = run;
    }
    __syncthreads();
    int off = partial[t];
    for (int i = 0; i < 20; i++) {
        int idx = base + i;
        if (idx < NNODES) start[idx] = off + loc[i];
    }
}

// swizzled LDS byte offset for [row][128B] tiles: XOR row bits into 16B-slot bits (G4)
__device__ __forceinline__ int swz(int row, int kbyte){
    return row * 128 + (kbyte ^ ((row & 7) << 4));
}
__device__ __forceinline__ bf16x8 ld_frag(const unsigned char* base, int row, int kbyte){
    return *reinterpret_cast<const bf16x8*>(base + swz(row, kbyte));
}
__device__ __forceinline__ bf16x8 ld_gfrag(const unsigned* base, int row, int kchunk){
    return *reinterpret_cast<const bf16x8*>(base + row * 32 + kchunk * 4);
}

// ---- edge stage: MFMA stages 1-3 + hs + lin_w0/1/2 GEMMs; payload = transformed msgs ----
__global__ __launch_bounds__(256, 2) void edge_kernel(
    const float* __restrict__ pos, const int* __restrict__ species,
    const int* __restrict__ senders, const int* __restrict__ receivers,
    const float* __restrict__ node_embed, const float* __restrict__ w1,
    const unsigned* __restrict__ w2tn_g, const unsigned* __restrict__ w3tn_g,
    const unsigned* __restrict__ linp_g,
    const int* __restrict__ start, int* __restrict__ cursor,
    unsigned* __restrict__ payload)
{
    __shared__ __align__(16) unsigned char a2l[8192];       // hid1 then hid2, swizzled
    __shared__ __align__(16) unsigned char rp[3 * 8192];    // (wts*hs) tiles per j, swizzled
    __shared__ __align__(16) unsigned short otl[64 * PAYL]; // out tile (payload rows)
    __shared__ unsigned short hsl[64 * 64];                 // sender embed bf16 [m][c]
    __shared__ float rbl[64 * 8];
    __shared__ int spl[64];
    __shared__ int slotl[64];

    int tid = threadIdx.x;
    int w = tid >> 6, l = tid & 63;
    int lrow = l & 15;
    int kh = l >> 4;           // k-quarter 0..3
    int lkb = kh * 16;         // byte offset within 64B k-half

    // prefetch stage-2 B frags from global (registers; overlaps phase A)
    bf16x8 w2b0[4], w2b1[4];
    #pragma unroll
    for (int nt = 0; nt < 4; nt++) {
        w2b0[nt] = ld_gfrag(w2tn_g, nt * 16 + lrow, kh);
        w2b1[nt] = ld_gfrag(w2tn_g, nt * 16 + lrow, 4 + kh);
    }

    // ---- phase A: per-edge geometry + CSR slot (one thread per edge) ----
    if (tid < 64) {
        int e = blockIdx.x * 64 + tid;
        int snd = senders[e];
        int rcv = receivers[e];
        slotl[tid] = start[rcv] + atomicAdd(&cursor[rcv], 1);
        spl[tid] = species[snd];

        float dx = pos[rcv * 3 + 0] - pos[snd * 3 + 0];
        float dy = pos[rcv * 3 + 1] - pos[snd * 3 + 1];
        float dz = pos[rcv * 3 + 2] - pos[snd * 3 + 2];
        float r = sqrtf(dx * dx + dy * dy + dz * dz);
        float rinv = 1.0f / (r + 1e-9f);
        float ux = dx * rinv, uy = dy * rinv, uz = dz * rinv;

        const float SQ3 = 1.7320508075688772f;
        const float S15 = 3.872983346207417f;
        const float S5  = 2.2360679774997896f;
        otl[tid * PAYL + 192] = bf16u(SQ3 * ux);
        otl[tid * PAYL + 193] = bf16u(SQ3 * uy);
        otl[tid * PAYL + 194] = bf16u(SQ3 * uz);
        otl[tid * PAYL + 195] = bf16u(S15 * ux * uy);
        otl[tid * PAYL + 196] = bf16u(S15 * uy * uz);
        otl[tid * PAYL + 197] = bf16u(0.5f * S5 * (3.0f * uz * uz - 1.0f));
        otl[tid * PAYL + 198] = bf16u(S15 * ux * uz);
        otl[tid * PAYL + 199] = bf16u(0.5f * S15 * (ux * ux - uy * uy));

        const float PI = 3.14159265358979323846f;
        float rc = r * 0.2f;
        float env = 0.5f * (__cosf(PI * fminf(rc, 1.0f)) + 1.0f);
        float scale = 0.6324555320336759f * rinv * env;
        #pragma unroll
        for (int b = 0; b < 8; b++)
            rbl[tid * 8 + b] = scale * __sinf((float)(b + 1) * PI * rc);
    }
    __syncthreads();

    // ---- hs fill: hsl[m][c] = bf16(node_embed[sp_m][c]) ----
    {
        int m = tid >> 2, c0 = (tid & 3) * 16;
        const float* hr = node_embed + spl[m] * 64 + c0;
        #pragma unroll
        for (int i = 0; i < 16; i++) hsl[m * 64 + c0 + i] = bf16u(hr[i]);
    }

    // ---- stage 1 (VALU, K=8): hid1[m][j] = silu(rb . w1[:,j]) -> a2l bf16 ----
    {
        int m = tid & 63;
        float r0 = rbl[m * 8 + 0], r1 = rbl[m * 8 + 1], r2 = rbl[m * 8 + 2], r3 = rbl[m * 8 + 3];
        float r4 = rbl[m * 8 + 4], r5 = rbl[m * 8 + 5], r6 = rbl[m * 8 + 6], r7 = rbl[m * 8 + 7];
        #pragma unroll
        for (int jp = 0; jp < 8; jp++) {
            int j = w * 16 + jp * 2;    // wave-uniform column -> scalar w1 loads
            float h0 = silu_f(r0 * w1[j]       + r1 * w1[64 + j]  + r2 * w1[128 + j] + r3 * w1[192 + j]
                            + r4 * w1[256 + j] + r5 * w1[320 + j] + r6 * w1[384 + j] + r7 * w1[448 + j]);
            float h1 = silu_f(r0 * w1[j + 1]     + r1 * w1[64 + j + 1]  + r2 * w1[128 + j + 1] + r3 * w1[192 + j + 1]
                            + r4 * w1[256 + j + 1] + r5 * w1[320 + j + 1] + r6 * w1[384 + j + 1] + r7 * w1[448 + j + 1]);
            *reinterpret_cast<unsigned*>(a2l + swz(m, j * 2)) = pk_bf16(h0, h1);
        }
    }
    __syncthreads();

    // ---- stage 2 MFMA: hid2 = silu(hid1 @ w2), M=64 K=64 N=64 ----
    {
        bf16x8 aF0 = ld_frag(a2l, 16 * w + lrow, lkb);
        bf16x8 aF1 = ld_frag(a2l, 16 * w + lrow, 64 + lkb);
        f32x4 acc[4];
        #pragma unroll
        for (int nt = 0; nt < 4; nt++) {
            f32x4 c = {0.f, 0.f, 0.f, 0.f};
            c = __builtin_amdgcn_mfma_f32_16x16x32_bf16(aF0, w2b0[nt], c, 0, 0, 0);
            c = __builtin_amdgcn_mfma_f32_16x16x32_bf16(aF1, w2b1[nt], c, 0, 0, 0);
            acc[nt] = c;
        }
        __syncthreads();   // all reads of a2l complete before overwrite
        #pragma unroll
        for (int nt = 0; nt < 4; nt++) {
            int n = nt * 16 + lrow;
            #pragma unroll
            for (int r = 0; r < 4; r++) {
                int m = 16 * w + kh * 4 + r;
                *reinterpret_cast<unsigned short*>(a2l + swz(m, n * 2)) = bf16u(silu_f(acc[nt][r]));
            }
        }
    }
    __syncthreads();

    // ---- stage 3 MFMA: wts*0.25 = hid2 @ w3q; epilogue *hs -> rp tiles (swizzled bf16) ----
    {
        bf16x8 w3b0[3], w3b1[3];
        #pragma unroll
        for (int nl = 0; nl < 3; nl++) {
            int o16 = (3 * w + nl) * 16 + lrow;
            w3b0[nl] = ld_gfrag(w3tn_g, o16, kh);
            w3b1[nl] = ld_gfrag(w3tn_g, o16, 4 + kh);
        }
        #pragma unroll
        for (int mt = 0; mt < 4; mt++) {
            bf16x8 a30 = ld_frag(a2l, 16 * mt + lrow, lkb);
            bf16x8 a31 = ld_frag(a2l, 16 * mt + lrow, 64 + lkb);
            #pragma unroll
            for (int nl = 0; nl < 3; nl++) {
                f32x4 c = {0.f, 0.f, 0.f, 0.f};
                c = __builtin_amdgcn_mfma_f32_16x16x32_bf16(a30, w3b0[nl], c, 0, 0, 0);
                c = __builtin_amdgcn_mfma_f32_16x16x32_bf16(a31, w3b1[nl], c, 0, 0, 0);
                int ntg = 3 * w + nl;
                int o = ntg * 16 + lrow;
                int j = ntg >> 2;
                int cc = o & 63;
                unsigned char* rpj = rp + j * 8192;
                #pragma unroll
                for (int r = 0; r < 4; r++) {
                    int m = 16 * mt + kh * 4 + r;
                    float hsf = bfu(hsl[m * 64 + cc]);
                    *reinterpret_cast<unsigned short*>(rpj + swz(m, cc * 2)) = bf16u(c[r] * hsf);
                }
            }
        }
    }
    __syncthreads();

    // ---- stage 4 MFMA: payload_j = (wts*hs) @ lin_wj, 3 GEMMs of 64x64x64 ----
    {
        #pragma unroll
        for (int nl = 0; nl < 3; nl++) {
            int ntg = 3 * w + nl;
            int j = ntg >> 2;
            int dt = ntg & 3;
            const unsigned* lbase = linp_g + j * 2048;
            bf16x8 lb0 = ld_gfrag(lbase, dt * 16 + lrow, kh);
            bf16x8 lb1 = ld_gfrag(lbase, dt * 16 + lrow, 4 + kh);
            const unsigned char* rpj = rp + j * 8192;
            #pragma unroll
            for (int mt = 0; mt < 4; mt++) {
                bf16x8 aR0 = ld_frag(rpj, 16 * mt + lrow, lkb);
                bf16x8 aR1 = ld_frag(rpj, 16 * mt + lrow, 64 + lkb);
                f32x4 c = {0.f, 0.f, 0.f, 0.f};
                c = __builtin_amdgcn_mfma_f32_16x16x32_bf16(aR0, lb0, c, 0, 0, 0);
                c = __builtin_amdgcn_mfma_f32_16x16x32_bf16(aR1, lb1, c, 0, 0, 0);
                int o = ntg * 16 + lrow;
                #pragma unroll
                for (int r = 0; r < 4; r++) {
                    int m = 16 * mt + kh * 4 + r;
                    otl[m * PAYL + o] = bf16u(c[r]);
                }
            }
        }
    }
    __syncthreads();

    // ---- coalesced copy: out tile rows -> payload rows at CSR slots ----
    {
        const uint4* ot4 = reinterpret_cast<const uint4*>(otl);
        uint4* pay4 = reinterpret_cast<uint4*>(payload);
        for (int i = tid; i < 64 * 25; i += 256) {
            int row = i / 25, q = i - row * 25;
            pay4[(size_t)slotl[row] * 25 + q] = ot4[row * 25 + q];
        }
    }
}

// ---- fused gather + gate + heads: one wave per node (transforms pre-applied at edge) ----
__global__ __launch_bounds__(256, 4) void node_kernel(
    const unsigned* __restrict__ payload, const int* __restrict__ start,
    const int* __restrict__ species, const float* __restrict__ skip_vec,
    const float* __restrict__ gate_w, const float* __restrict__ focus_w,
    const float* __restrict__ focus_b, const int* __restrict__ flags,
    const float* __restrict__ species_w, const float* __restrict__ species_b,
    float* __restrict__ out_focus, float* __restrict__ out_species,
    float* __restrict__ focus_emb)
{
    int wave = threadIdx.x >> 6;
    int lane = threadIdx.x & 63;
    int n = blockIdx.x * 4 + wave;

    __shared__ float ss[4][64];

    // gather: dual accumulator sets to break the FMA dependency chain
    float a0 = 0, a1x = 0, a1y = 0, a1z = 0;
    float a2a = 0, a2b = 0, a2c = 0, a2d = 0, a2e = 0;
    float c0 = 0, c1x = 0, c1y = 0, c1z = 0;
    float c2a = 0, c2b = 0, c2c = 0, c2d = 0, c2e = 0;
    int s0 = start[n], s1 = start[n + 1];
    int i = s0;
    for (; i + 1 < s1; i += 2) {
        const unsigned short* pA = (const unsigned short*)(payload + (size_t)i * (PAYL / 2));
        const unsigned short* pB = (const unsigned short*)(payload + (size_t)(i + 1) * (PAYL / 2));
        float Ab0 = bfu(pA[lane]);
        float Ab1 = bfu(pA[64 + lane]);
        float Ab2 = bfu(pA[128 + lane]);
        uint4 Asv = *reinterpret_cast<const uint4*>(pA + 192);
        float Bb0 = bfu(pB[lane]);
        float Bb1 = bfu(pB[64 + lane]);
        float Bb2 = bfu(pB[128 + lane]);
        uint4 Bsv = *reinterpret_cast<const uint4*>(pB + 192);
        a0  += Ab0;
        a1x += Ab1 * bf_lo(Asv.x); a1y += Ab1 * bf_hi(Asv.x); a1z += Ab1 * bf_lo(Asv.y);
        a2a += Ab2 * bf_hi(Asv.y); a2b += Ab2 * bf_lo(Asv.z); a2c += Ab2 * bf_hi(Asv.z);
        a2d += Ab2 * bf_lo(Asv.w); a2e += Ab2 * bf_hi(Asv.w);
        c0  += Bb0;
        c1x += Bb1 * bf_lo(Bsv.x); c1y += Bb1 * bf_hi(Bsv.x); c1z += Bb1 * bf_lo(Bsv.y);
        c2a += Bb2 * bf_hi(Bsv.y); c2b += Bb2 * bf_lo(Bsv.z); c2c += Bb2 * bf_hi(Bsv.z);
        c2d += Bb2 * bf_lo(Bsv.w); c2e += Bb2 * bf_hi(Bsv.w);
    }
    if (i < s1) {
        const unsigned short* pA = (const unsigned short*)(payload + (size_t)i * (PAYL / 2));
        float Ab0 = bfu(pA[lane]);
        float Ab1 = bfu(pA[64 + lane]);
        float Ab2 = bfu(pA[128 + lane]);
        uint4 Asv = *reinterpret_cast<const uint4*>(pA + 192);
        a0  += Ab0;
        a1x += Ab1 * bf_lo(Asv.x); a1y += Ab1 * bf_hi(Asv.x); a1z += Ab1 * bf_lo(Asv.y);
        a2a += Ab2 * bf_hi(Asv.y); a2b += Ab2 * bf_lo(Asv.z); a2c += Ab2 * bf_hi(Asv.z);
        a2d += Ab2 * bf_lo(Asv.w); a2e += Ab2 * bf_hi(Asv.w);
    }
    // combine dual sets: these ARE s (pre-skip), v, t directly (lin applied at edge)
    float s  = a0 + c0 + skip_vec[species[n] * 64 + lane];
    float v0 = a1x + c1x, v1 = a1y + c1y, v2 = a1z + c1z;
    float t0 = a2a + c2a, t1 = a2b + c2b, t2 = a2c + c2c, t3 = a2d + c2d, t4 = a2e + c2e;

    ss[wave][lane] = s;
    float g1a = 0.0f, g2a = 0.0f;
    #pragma unroll 4
    for (int c = 0; c < 64; c++) {
        float sc = ss[wave][c];
        g1a += sc * gate_w[c * 128 + lane];
        g2a += sc * gate_w[c * 128 + 64 + lane];
    }
    float g1 = sigm_f(g1a), g2 = sigm_f(g2a);
    float s_out = s * sigm_f(s);
    float vo0 = v0 * g1, vo1 = v1 * g1, vo2 = v2 * g1;
    float to0 = t0 * g2, to1 = t1 * g2, to2 = t2 * g2, to3 = t3 * g2, to4 = t4 * g2;

    float pfo = s_out * focus_w[lane]
              + vo0 * focus_w[64 + lane * 3 + 0]
              + vo1 * focus_w[64 + lane * 3 + 1]
              + vo2 * focus_w[64 + lane * 3 + 2]
              + to0 * focus_w[256 + lane * 5 + 0]
              + to1 * focus_w[256 + lane * 5 + 1]
              + to2 * focus_w[256 + lane * 5 + 2]
              + to3 * focus_w[256 + lane * 5 + 3]
              + to4 * focus_w[256 + lane * 5 + 4];
    #pragma unroll
    for (int off = 32; off > 0; off >>= 1) pfo += __shfl_down(pfo, off);
    if (lane == 0) out_focus[n] = pfo + focus_b[0];

    int fg = flags[n];
    if (fg) {
        float* fe = focus_emb + (size_t)(fg - 1) * FLATDIM;
        fe[lane] = s_out;
        fe[64 + lane * 3 + 0] = vo0;
        fe[64 + lane * 3 + 1] = vo1;
        fe[64 + lane * 3 + 2] = vo2;
        fe[256 + lane * 5 + 0] = to0;
        fe[256 + lane * 5 + 1] = to1;
        fe[256 + lane * 5 + 2] = to2;
        fe[256 + lane * 5 + 3] = to3;
        fe[256 + lane * 5 + 4] = to4;

        // species head: 5 logits via wave reduction
        #pragma unroll
        for (int j = 0; j < 5; j++) {
            float acc = s_out * species_w[lane * 5 + j]
                      + vo0 * species_w[(64 + lane * 3 + 0) * 5 + j]
                      + vo1 * species_w[(64 + lane * 3 + 1) * 5 + j]
                      + vo2 * species_w[(64 + lane * 3 + 2) * 5 + j]
                      + to0 * species_w[(256 + lane * 5 + 0) * 5 + j]
                      + to1 * species_w[(256 + lane * 5 + 1) * 5 + j]
                      + to2 * species_w[(256 + lane * 5 + 2) * 5 + j]
                      + to3 * species_w[(256 + lane * 5 + 3) * 5 + j]
                      + to4 * species_w[(256 + lane * 5 + 4) * 5 + j];
            #pragma unroll
            for (int off = 32; off > 0; off >>= 1) acc += __shfl_down(acc, off);
            if (lane == 0) out_species[(fg - 1) * 5 + j] = acc + species_b[j];
        }
    }
}

// ---- pos head: grid = 100 graphs x 8 k-splits; bf16 weights; atomicAdd combine ----
__global__ __launch_bounds__(256) void pos_kernel(
    const float* __restrict__ focus_emb, const int* __restrict__ target_species,
    const float* __restrict__ species_embed,
    const unsigned* __restrict__ posw_bf, const float* __restrict__ pos_b,
    float* __restrict__ out_pos)
{
    int g  = blockIdx.x >> 3;
    int ks = blockIdx.x & 7;
    int k0 = ks * 80;
    int tid = threadIdx.x;
    __shared__ float pin[80];

    if (tid < 80) {
        int k = k0 + tid;
        pin[tid] = (k < FLATDIM) ? focus_emb[(size_t)g * FLATDIM + k]
                                 : species_embed[target_species[g] * CC + (k - FLATDIM)];
    }
    __syncthreads();

    if (tid < 200) {
        float a0 = 0, a1 = 0, a2 = 0, a3 = 0, a4 = 0, a5 = 0, a6 = 0, a7 = 0;
        const unsigned* wp = posw_bf + (size_t)k0 * 800 + tid * 4;
        #pragma unroll 4
        for (int kk = 0; kk < 80; kk++) {
            uint4 wv = *reinterpret_cast<const uint4*>(wp + (size_t)kk * 800);
            float p = pin[kk];
            a0 += p * bf_lo(wv.x); a1 += p * bf_hi(wv.x);
            a2 += p * bf_lo(wv.y); a3 += p * bf_hi(wv.y);
            a4 += p * bf_lo(wv.z); a5 += p * bf_hi(wv.z);
            a6 += p * bf_lo(wv.w); a7 += p * bf_hi(wv.w);
        }
        float* op = out_pos + (size_t)g * POSOUT + tid * 8;
        if (ks == 0) {
            const float* bb = pos_b + tid * 8;
            atomicAdd(op + 0, a0 + bb[0]); atomicAdd(op + 1, a1 + bb[1]);
            atomicAdd(op + 2, a2 + bb[2]); atomicAdd(op + 3, a3 + bb[3]);
            atomicAdd(op + 4, a4 + bb[4]); atomicAdd(op + 5, a5 + bb[5]);
            atomicAdd(op + 6, a6 + bb[6]); atomicAdd(op + 7, a7 + bb[7]);
        } else {
            atomicAdd(op + 0, a0); atomicAdd(op + 1, a1);
            atomicAdd(op + 2, a2); atomicAdd(op + 3, a3);
            atomicAdd(op + 4, a4); atomicAdd(op + 5, a5);
            atomicAdd(op + 6, a6); atomicAdd(op + 7, a7);
        }
    }
}

extern "C" void kernel_launch(void* const* d_in, const int* in_sizes, int n_in,
                              void* d_out, int out_size, void* d_ws, size_t ws_size,
                              hipStream_t stream) {
    const float* positions      = (const float*)d_in[0];
    const int*   species        = (const int*)  d_in[1];
    const int*   senders        = (const int*)  d_in[2];
    const int*   receivers      = (const int*)  d_in[3];
    const int*   n_node         = (const int*)  d_in[4];
    const int*   target_species = (const int*)  d_in[5];
    const float* species_embed  = (const float*)d_in[6];
    const float* node_embed     = (const float*)d_in[7];
    const float* radial_w1      = (const float*)d_in[8];
    const float* radial_w2      = (const float*)d_in[9];
    const float* radial_w3      = (const float*)d_in[10];
    const float* lin_w0         = (const float*)d_in[11];
    const float* lin_w1         = (const float*)d_in[12];
    const float* lin_w2         = (const float*)d_in[13];
    const float* skip_w         = (const float*)d_in[14];
    const float* gate_w         = (const float*)d_in[15];
    const float* focus_w        = (const float*)d_in[16];
    const float* focus_b        = (const float*)d_in[17];
    const float* species_w      = (const float*)d_in[18];
    const float* species_b      = (const float*)d_in[19];
    const float* pos_w          = (const float*)d_in[20];
    const float* pos_b          = (const float*)d_in[21];

    // ws layout:
    //   payload [320000*100 u32 = 128MB]
    // | posw_bf [640*800 u32 = 2.05MB]
    // | degree[20000] cursor[20000] flags[20000] start[20001] (ints)
    // | w2tn_g[2048 u32] w3tn_g[6144 u32] linp_g[6144 u32]
    // | skip_vec[320 f32] | focus_emb[57600 f32]
    unsigned* payload = (unsigned*)d_ws;
    unsigned* posw_bf = payload + (size_t)NEDGES * (PAYL / 2);
    int* degree = (int*)(posw_bf + 640 * 800);
    int* cursor = degree + NNODES;
    int* flags  = cursor + NNODES;
    int* start  = flags + NNODES;
    unsigned* w2tn_g = (unsigned*)(start + NNODES + 1);
    unsigned* w3tn_g = w2tn_g + 2048;
    unsigned* linp_g = w3tn_g + 6144;
    float* skip_vec  = (float*)(linp_g + 6144);
    float* focus_emb = skip_vec + 320;

    float* out       = (float*)d_out;
    float* out_focus = out;
    float* out_spec  = out + NNODES;
    float* out_pos   = out + NNODES + NGRAPHS * 5;

    hipMemsetAsync(degree, 0, 3 * NNODES * sizeof(int), stream);
    hipMemsetAsync(out_pos, 0, (size_t)NGRAPHS * POSOUT * sizeof(float), stream);

    prep_kernel<<<256, 256, 0, stream>>>(radial_w2, radial_w3, lin_w0, lin_w1, lin_w2,
                                         skip_w, node_embed, pos_w, n_node, receivers,
                                         w2tn_g, w3tn_g, linp_g, skip_vec, posw_bf,
                                         flags, degree);
    scan_kernel<<<1, 1024, 0, stream>>>(degree, start);
    edge_kernel<<<NEDGES / 64, 256, 0, stream>>>(
        positions, species, senders, receivers, node_embed, radial_w1,
        w2tn_g, w3tn_g, linp_g, start, cursor, payload);

    node_kernel<<<NNODES / 4, 256, 0, stream>>>(
        payload, start, species, skip_vec,
        gate_w, focus_w, focus_b, flags,
        species_w, species_b, out_focus, out_spec, focus_emb);

    pos_kernel<<<NGRAPHS * 8, 256, 0, stream>>>(
        focus_emb, target_species, species_embed, posw_bf, pos_b, out_pos);
}